// Round 8
// baseline (255.776 us; speedup 1.0000x reference)
//
#include <hip/hip_runtime.h>
#include <math.h>

#define BB 256
#define DD 4096
#define MAXR 31
#define NCAND 4
#define CAPW 192
// filter: u < U_THRESH  =>  g(u) < 3.8 (incl. fp32 rounding slop). GUARD=4.0 check.
#define U_THRESH 0.9778f
#define GUARD 4.0f

typedef unsigned short u16;
typedef u16 u16x8 __attribute__((ext_vector_type(8)));
typedef __bf16 bf16x8 __attribute__((ext_vector_type(8)));
typedef float f32x16 __attribute__((ext_vector_type(16)));

// ---------------- threefry2x32 (JAX schedule), forced v_alignbit rotate ----------------
__device__ __forceinline__ void tf2x32(unsigned k0, unsigned k1, unsigned c0, unsigned c1,
                                       unsigned &o0, unsigned &o1) {
  unsigned ks2 = k0 ^ k1 ^ 0x1BD11BDAu;
  unsigned x0 = c0 + k0;
  unsigned x1 = c1 + k1;
#define TF_R(r) { x0 += x1; x1 = __builtin_rotateleft32(x1, r); x1 ^= x0; }
  TF_R(13) TF_R(15) TF_R(26) TF_R(6)   x0 += k1;  x1 += ks2 + 1u;
  TF_R(17) TF_R(29) TF_R(16) TF_R(24)  x0 += ks2; x1 += k0 + 2u;
  TF_R(13) TF_R(15) TF_R(26) TF_R(6)   x0 += k0;  x1 += k1 + 3u;
  TF_R(17) TF_R(29) TF_R(16) TF_R(24)  x0 += k1;  x1 += ks2 + 4u;
  TF_R(13) TF_R(15) TF_R(26) TF_R(6)   x0 += ks2; x1 += k0 + 5u;
#undef TF_R
  o0 = x0; o1 = x1;
}

__device__ __forceinline__ unsigned tf_xor(unsigned k0, unsigned k1, unsigned c0, unsigned c1) {
  unsigned a, b; tf2x32(k0, k1, c0, c1, a, b); return a ^ b;
}

__device__ __forceinline__ float bits_to_unit(unsigned bits) {
  return __uint_as_float(0x3f800000u | (bits >> 9)) - 1.0f;
}

// sampling key for step j (bit-identical to the original k_rng chain); block-uniform -> SALU
__device__ __forceinline__ void keys_of(int j, unsigned &kk0, unsigned &kk1) {
  unsigned ks0, ks1;
  tf2x32(0u, 42u, 0u, 1u, ks0, ks1);
  tf2x32(ks0, ks1, 0u, (unsigned)j, kk0, kk1);
}

__device__ __forceinline__ int radius_of(int b) {
  unsigned krad0, krad1, k10, k11, k20, k21;
  tf2x32(0u, 42u, 0u, 0u, krad0, krad1);
  tf2x32(krad0, krad1, 0u, 0u, k10, k11);
  tf2x32(krad0, krad1, 0u, 1u, k20, k21);
  unsigned hi = tf_xor(k10, k11, 0u, (unsigned)b);
  unsigned lo = tf_xor(k20, k21, 0u, (unsigned)b);
  return 1 + (int)(((hi % 31u) * 4u + (lo % 31u)) % 31u);
}

__device__ __forceinline__ float uacc_of(int b) {
  unsigned ka0, ka1;
  tf2x32(0u, 42u, 0u, 2u, ka0, ka1);
  return bits_to_unit(tf_xor(ka0, ka1, 0u, (unsigned)b));
}

// ---------------- fast accurate double log (~1e-13 rel) ----------------
__device__ __forceinline__ double dlog(double x) {
  unsigned long long ub = (unsigned long long)__double_as_longlong(x);
  int e = (int)((ub >> 52) & 0x7FFull) - 1022;
  double m = __longlong_as_double((long long)((ub & 0x000FFFFFFFFFFFFFull) | 0x3FE0000000000000ull));
  if (m < 0.70710678118654752440) { m *= 2.0; e -= 1; }
  double r = (m - 1.0) / (m + 1.0);
  double z = r * r;
  double s = fma(z, fma(z, fma(z, fma(z, fma(z, fma(z, 1.0/15.0, 1.0/13.0),
                1.0/11.0), 1.0/9.0), 1.0/7.0), 1.0/5.0), 1.0/3.0);
  double t2 = 2.0 * r;
  return fma((double)e, 0.69314718055994530942, fma(t2 * z, s, t2));
}

// gumbel from uniform u (u>0), fp32-rounded at each log (matches XLA)
__device__ __forceinline__ float gumbel_from_u(float f) {
  float uu = (f == 0.0f) ? 1.17549435e-38f : f;
  float t1 = (float)dlog((double)uu);
  return -(float)dlog((double)(-t1));
}

__device__ __forceinline__ float gumbel_of(unsigned kk0, unsigned kk1, unsigned n) {
  return gumbel_from_u(bits_to_unit(tf_xor(kk0, kk1, 0u, n)));
}

// 1024-thread double reduce (16 waves)
__device__ __forceinline__ double blockReduce1024(double v, double* lds) {
  int t = threadIdx.x;
  #pragma unroll
  for (int off = 32; off > 0; off >>= 1) v += __shfl_down(v, off);
  __syncthreads();
  if ((t & 63) == 0) lds[t >> 6] = v;
  __syncthreads();
  double s = 0.0;
  #pragma unroll
  for (int i = 0; i < 16; i++) s += lds[i];
  return s;
}

// ---------------- W 3-way bf16 split ----------------
__device__ __forceinline__ void split3(float w, u16 &h, u16 &l, u16 &q) {
  __bf16 hb = (__bf16)w;
  float r = w - (float)hb;        // exact
  __bf16 lb = (__bf16)r;
  float r2 = r - (float)lb;       // exact
  __bf16 qb = (__bf16)r2;
  h = __builtin_bit_cast(u16, hb);
  l = __builtin_bit_cast(u16, lb);
  q = __builtin_bit_cast(u16, qb);
}

// ---------------- K_GEMM: pure 128x64-tile bf16 3-split MFMA GEMM ----------------
__global__ __launch_bounds__(256, 2) void k_gemm(
    const float* __restrict__ x, const float* __restrict__ W,
    float* __restrict__ Cpart, int klen) {
  int t = threadIdx.x;
  int g = blockIdx.x;
  int nt = g & 63, mt = (g >> 6) & 1, kc = g >> 7;
  int k0 = kc * klen;

  __shared__ alignas(16) u16 As[4][128][8];     // 8 KB  (x tile bf16)
  __shared__ alignas(16) u16 Bs[3][4][64][8];   // 12 KB (Wh/Wl/Wl2)

  const float* xrow = x + (size_t)(mt * 128) * DD + k0;
  const float* wrow = W + (size_t)(nt * 64) * DD + k0;   // W symmetric: rows give B^T

  int am = t >> 2, akg = t & 3;
  int bn = t >> 2, bkg = t & 3;

  float4 aR0, aR1, aR2, aR3;
  float4 bR0, bR1;
  int nsteps = klen / 32;

  { // prefetch step 0
    const float* ap = xrow + (size_t)am * DD + akg * 8;
    aR0 = *(const float4*)ap;       aR1 = *(const float4*)(ap + 4);
    const float* ap2 = ap + (size_t)64 * DD;
    aR2 = *(const float4*)ap2;      aR3 = *(const float4*)(ap2 + 4);
    const float* wp = wrow + (size_t)bn * DD + bkg * 8;
    bR0 = *(const float4*)wp;       bR1 = *(const float4*)(wp + 4);
  }

  int wid = t >> 6, lane = t & 63;
  int wr = (wid >> 1) * 64, wc = (wid & 1) * 32;
  int lm = lane & 31, lh = lane >> 5;

  f32x16 acc[2];
  #pragma unroll
  for (int i = 0; i < 2; i++)
    #pragma unroll
    for (int r = 0; r < 16; r++) acc[i][r] = 0.0f;

  for (int s = 0; s < nsteps; s++) {
    __syncthreads();
    { // A convert (exact: x in {0,1}) + write
      float af32[8];
      *(float4*)&af32[0] = aR0; *(float4*)&af32[4] = aR1;
      u16x8 av;
      #pragma unroll
      for (int i = 0; i < 8; i++) av[i] = __builtin_bit_cast(u16, (__bf16)af32[i]);
      *(u16x8*)&As[akg][am][0] = av;
      *(float4*)&af32[0] = aR2; *(float4*)&af32[4] = aR3;
      #pragma unroll
      for (int i = 0; i < 8; i++) av[i] = __builtin_bit_cast(u16, (__bf16)af32[i]);
      *(u16x8*)&As[akg][am + 64][0] = av;
    }
    { // B split3 + write 3 planes
      float wv[8];
      *(float4*)&wv[0] = bR0; *(float4*)&wv[4] = bR1;
      u16x8 ph, pl, pq;
      #pragma unroll
      for (int i = 0; i < 8; i++) {
        u16 hh, ll, qq;
        split3(wv[i], hh, ll, qq);
        ph[i] = hh; pl[i] = ll; pq[i] = qq;
      }
      *(u16x8*)&Bs[0][bkg][bn][0] = ph;
      *(u16x8*)&Bs[1][bkg][bn][0] = pl;
      *(u16x8*)&Bs[2][bkg][bn][0] = pq;
    }
    __syncthreads();
    if (s + 1 < nsteps) { // prefetch next step
      int kk = (s + 1) * 32;
      const float* ap = xrow + (size_t)am * DD + kk + akg * 8;
      aR0 = *(const float4*)ap;       aR1 = *(const float4*)(ap + 4);
      const float* ap2 = ap + (size_t)64 * DD;
      aR2 = *(const float4*)ap2;      aR3 = *(const float4*)(ap2 + 4);
      const float* wp = wrow + (size_t)bn * DD + kk + bkg * 8;
      bR0 = *(const float4*)wp;       bR1 = *(const float4*)(wp + 4);
    }
    bf16x8 af[2][2];
    #pragma unroll
    for (int mf = 0; mf < 2; mf++)
      #pragma unroll
      for (int h = 0; h < 2; h++)
        af[mf][h] = *(const bf16x8*)&As[2 * h + lh][wr + mf * 32 + lm][0];
    #pragma unroll
    for (int p = 0; p < 3; p++) {
      bf16x8 b0 = *(const bf16x8*)&Bs[p][lh][wc + lm][0];
      bf16x8 b1 = *(const bf16x8*)&Bs[p][2 + lh][wc + lm][0];
      #pragma unroll
      for (int mf = 0; mf < 2; mf++) {
        acc[mf] = __builtin_amdgcn_mfma_f32_32x32x16_bf16(af[mf][0], b0, acc[mf], 0, 0, 0);
        acc[mf] = __builtin_amdgcn_mfma_f32_32x32x16_bf16(af[mf][1], b1, acc[mf], 0, 0, 0);
      }
    }
  }

  float* Cp = Cpart + (size_t)kc * ((size_t)BB * DD);
  #pragma unroll
  for (int mf = 0; mf < 2; mf++) {
    int col   = nt * 64 + wc + lm;
    int rbase = mt * 128 + wr + mf * 32 + 4 * lh;
    #pragma unroll
    for (int r = 0; r < 16; r++) {
      int row = rbase + (r & 3) + 8 * (r >> 2);
      Cp[(size_t)row * DD + col] = acc[mf][r];
    }
  }
}

// ---------------- K_TAIL: filter + everything after the GEMM, one block per row ----------
// phases: A reduce+score  B filter+top4 fused (one j per wave)  (B') exact fallback
//         C chain-select  D y/grad_y/score_y                    E accept+output
__global__ __launch_bounds__(1024) void k_tail(
    const float* __restrict__ Cpart, const float* __restrict__ bias,
    const float* __restrict__ x, const float* __restrict__ W,
    float* __restrict__ out, int KS) {
  int b = blockIdx.x, t = threadIdx.x;

  __shared__ float sc_lds[DD];            // 16 KB: sc_x
  __shared__ float gr_lds[DD];            // 16 KB: grad_x, then sc_y
  __shared__ unsigned stg_b[16][CAPW];    // 12 KB: staged threefry bits per wave
  __shared__ u16      stg_d[16][CAPW];    // 6 KB:  staged indices per wave
  __shared__ int      wcnt[16];
  __shared__ double redbuf[16];
  __shared__ float lmx[16];
  __shared__ float ls_v[16];
  __shared__ int   ls_i[16];
  __shared__ int   win_i[4];
  __shared__ int   cand_lds[MAXR][NCAND];
  __shared__ int   fb_list[MAXR];
  __shared__ int   nfb_s;
  __shared__ int   fidx[MAXR];
  __shared__ float fsgn[MAXR];
  __shared__ unsigned mask[DD / 32];
  __shared__ int   pick_s;
  __shared__ int   nf_s;
  __shared__ float scmax_s;
  __shared__ double score_x_s, score_y_s, Ssum_s, Tsum_s;
  __shared__ float scx_s[MAXR], scy_s[MAXR];
  __shared__ float accf;

  // ================= phase A: split-K reduce, sc_x, score_x, scmax, S =================
  int d0 = t * 4;
  size_t o = (size_t)b * DD + d0;
  float a0 = 0.f, a1 = 0.f, a2 = 0.f, a3 = 0.f;
  for (int kc = 0; kc < KS; kc++) {
    float4 c = *(const float4*)&Cpart[(size_t)kc * BB * DD + o];
    a0 += c.x; a1 += c.y; a2 += c.z; a3 += c.w;
  }
  float4 bv4 = *(const float4*)&bias[d0];
  float4 xv4 = *(const float4*)&x[o];
  float gg[4] = { a0 + bv4.x, a1 + bv4.y, a2 + bv4.z, a3 + bv4.w };
  float xx[4] = { xv4.x, xv4.y, xv4.z, xv4.w };
  float bb[4] = { bv4.x, bv4.y, bv4.z, bv4.w };
  float scv[4];
  double s1 = 0.0, s2 = 0.0;
  float mx = -INFINITY;
  #pragma unroll
  for (int k = 0; k < 4; k++) {
    scv[k] = (1.0f - 2.0f * xx[k]) * gg[k] * 0.5f;
    mx = fmaxf(mx, scv[k]);
    s1 += (double)xx[k] * (double)gg[k];
    s2 += (double)xx[k] * (double)bb[k];
  }
  *(float4*)&sc_lds[d0] = *(float4*)&scv[0];
  *(float4*)&gr_lds[d0] = *(float4*)&gg[0];
  if (t < 128) mask[t] = 0u;
  if (t < 16) wcnt[t] = 0;
  if (t == 0) { nf_s = radius_of(b); nfb_s = 0; }
  double sx = exp((double)scv[0]) + exp((double)scv[1]) + exp((double)scv[2]) + exp((double)scv[3]);
  double S1 = blockReduce1024(s1, redbuf);
  double S2 = blockReduce1024(s2, redbuf);
  double Sv = blockReduce1024(sx, redbuf);
  #pragma unroll
  for (int off = 32; off > 0; off >>= 1) mx = fmaxf(mx, __shfl_down(mx, off));
  __syncthreads();
  if ((t & 63) == 0) lmx[t >> 6] = mx;
  __syncthreads();
  if (t == 0) {
    float m = lmx[0];
    #pragma unroll
    for (int i = 1; i < 16; i++) m = fmaxf(m, lmx[i]);
    score_x_s = 0.5 * (S1 + S2);
    scmax_s = m;
    Ssum_s = Sv;
  }
  __syncthreads();

  // ======== phase B: filter + top-4 fused, one j per wave ========
  {
    int wv = t >> 6, ln = t & 63;
    float scmax_l = scmax_s;
    const unsigned KMIN = (unsigned)ceil((double)U_THRESH * 8388608.0);
    unsigned base_c = (unsigned)(b * DD);
    for (int pass = 0; pass < 2; pass++) {
      int j = pass * 16 + wv;
      bool active = (j < MAXR);
      unsigned kk0 = 0, kk1 = 0;
      if (active) {
        keys_of(j, kk0, kk1);
        // stage: hash the full row, compact passers into this wave's LDS slice
        unsigned d = (unsigned)ln;
        #pragma unroll 8
        for (int q = 0; q < 64; q++) {
          unsigned bits = tf_xor(kk0, kk1, 0u, base_c + d);
          if ((bits >> 9) >= KMIN) {
            int pos = atomicAdd(&wcnt[wv], 1);
            if (pos < CAPW) { stg_d[wv][pos] = (u16)d; stg_b[wv][pos] = bits; }
          }
          d += 64;
        }
      }
      __syncthreads();
      if (active) {
        int n = wcnt[wv];
        bool fastok = (n <= CAPW) && (n >= NCAND);
        float v4 = -INFINITY;
        if (fastok) {
          float vv[3]; int dd[3]; unsigned alive = 0u;
          #pragma unroll
          for (int q = 0; q < 3; q++) {
            int idx = ln + 64 * q;
            if (idx < n) {
              int d = (int)stg_d[wv][idx];
              float f = bits_to_unit(stg_b[wv][idx]);
              vv[q] = sc_lds[d] + gumbel_from_u(f);
              dd[q] = d;
              alive |= 1u << q;
            } else { vv[q] = -INFINITY; dd[q] = 0x7FFFFFFF; }
          }
          for (int r = 0; r < NCAND; r++) {
            float bv = -INFINITY; int bi = 0x7FFFFFFF;
            #pragma unroll
            for (int q = 0; q < 3; q++)
              if (((alive >> q) & 1u) && (vv[q] > bv || (vv[q] == bv && dd[q] < bi))) { bv = vv[q]; bi = dd[q]; }
            #pragma unroll
            for (int off = 1; off < 64; off <<= 1) {
              float ov = __shfl_xor(bv, off);
              int   oi = __shfl_xor(bi, off);
              if (ov > bv || (ov == bv && oi < bi)) { bv = ov; bi = oi; }
            }
            // all 64 lanes agree on (bv, bi)
            if (ln == 0) cand_lds[j][r] = bi;
            v4 = bv;
            #pragma unroll
            for (int q = 0; q < 3; q++) if (dd[q] == bi) alive &= ~(1u << q);
          }
        }
        if (ln == 0) {
          bool needfb = !fastok || (v4 < scmax_l + GUARD);
          if (needfb) fb_list[atomicAdd(&nfb_s, 1)] = j;
        }
      }
      __syncthreads();
      if (t < 16) wcnt[t] = 0;
      __syncthreads();
    }
  }

  // ================= phase B': exact fallback (statistically ~never) =================
  int nfb = nfb_s;
  for (int fi = 0; fi < nfb; fi++) {
    int j = fb_list[fi];
    unsigned kk0, kk1;
    keys_of(j, kk0, kk1);
    float vq[4]; int dq[4];
    unsigned alive = 0xFu;
    #pragma unroll
    for (int q = 0; q < 4; q++) {
      int d = t * 4 + q;
      vq[q] = sc_lds[d] + gumbel_of(kk0, kk1, (unsigned)(b * DD + d));
      dq[q] = d;
    }
    for (int r = 0; r < NCAND; r++) {
      float lv = -INFINITY; int li = 0x7FFFFFFF;
      #pragma unroll
      for (int q = 0; q < 4; q++)
        if (((alive >> q) & 1u) && (vq[q] > lv || (vq[q] == lv && dq[q] < li))) { lv = vq[q]; li = dq[q]; }
      #pragma unroll
      for (int off = 32; off > 0; off >>= 1) {
        float ov = __shfl_down(lv, off);
        int   oi = __shfl_down(li, off);
        if (ov > lv || (ov == lv && oi < li)) { lv = ov; li = oi; }
      }
      if ((t & 63) == 0) { ls_v[t >> 6] = lv; ls_i[t >> 6] = li; }
      __syncthreads();
      if (t == 0) {
        float fv = ls_v[0]; int fi2 = ls_i[0];
        #pragma unroll
        for (int w = 1; w < 16; w++)
          if (ls_v[w] > fv || (ls_v[w] == fv && ls_i[w] < fi2)) { fv = ls_v[w]; fi2 = ls_i[w]; }
        cand_lds[j][r] = fi2;
        win_i[0] = fi2;
      }
      __syncthreads();
      int wi = win_i[0];
      #pragma unroll
      for (int q = 0; q < 4; q++) if (dq[q] == wi) alive &= ~(1u << q);
    }
    __syncthreads();
  }

  // ================= phase C: blocked-chain resolution =================
  int jdone = 0;
  while (true) {
    if (t == 0) {
      int j = jdone;
      while (j < MAXR) {
        int pick = -1;
        #pragma unroll
        for (int r = 0; r < NCAND; r++) {
          int idx = cand_lds[j][r];
          if (pick < 0 && !((mask[idx >> 5] >> (idx & 31)) & 1u)) pick = idx;
        }
        if (pick < 0) break;
        fidx[j] = pick;
        mask[pick >> 5] |= (1u << (pick & 31));
        j++;
      }
      pick_s = j;
    }
    __syncthreads();
    int jf = pick_s;
    if (jf >= MAXR) break;
    { // cooperative exact fallback for step jf
      unsigned kk0, kk1;
      keys_of(jf, kk0, kk1);
      float lv = -INFINITY; int li = 0x7FFFFFFF;
      #pragma unroll
      for (int q = 0; q < 4; q++) {
        int d = t * 4 + q;
        if ((mask[d >> 5] >> (d & 31)) & 1u) continue;
        float vv = sc_lds[d] + gumbel_of(kk0, kk1, (unsigned)(b * DD + d));
        if (vv > lv || (vv == lv && d < li)) { lv = vv; li = d; }
      }
      #pragma unroll
      for (int off = 32; off > 0; off >>= 1) {
        float ov = __shfl_down(lv, off);
        int   oi = __shfl_down(li, off);
        if (ov > lv || (ov == lv && oi < li)) { lv = ov; li = oi; }
      }
      if ((t & 63) == 0) { ls_v[t >> 6] = lv; ls_i[t >> 6] = li; }
      __syncthreads();
      if (t == 0) {
        float fv = ls_v[0]; int fi2 = ls_i[0];
        #pragma unroll
        for (int w = 1; w < 16; w++)
          if (ls_v[w] > fv || (ls_v[w] == fv && ls_i[w] < fi2)) { fv = ls_v[w]; fi2 = ls_i[w]; }
        fidx[jf] = fi2;
        mask[fi2 >> 5] |= (1u << (fi2 & 31));
      }
      __syncthreads();
    }
    jdone = jf + 1;
  }

  int nf = nf_s;
  if (t < nf) fsgn[t] = 1.0f - 2.0f * x[(size_t)b * DD + fidx[t]];
  __syncthreads();

  // ================= phase D: y, grad_y, sc_y, score_y, T =================
  float gd[4] = { gr_lds[d0], gr_lds[d0 + 1], gr_lds[d0 + 2], gr_lds[d0 + 3] };
  float yy[4] = { xx[0], xx[1], xx[2], xx[3] };
  for (int jj = 0; jj < nf; jj++) {
    int fd = fidx[jj];
    float s = fsgn[jj];
    float4 wv = *(const float4*)&W[(size_t)fd * DD + d0];
    gd[0] = fmaf(s, wv.x, gd[0]);
    gd[1] = fmaf(s, wv.y, gd[1]);
    gd[2] = fmaf(s, wv.z, gd[2]);
    gd[3] = fmaf(s, wv.w, gd[3]);
    int r = fd - d0;
    if (r >= 0 && r < 4) yy[r] = 1.0f - xx[r];
  }
  float scy[4];
  double t1 = 0.0, t2 = 0.0;
  #pragma unroll
  for (int k = 0; k < 4; k++) {
    scy[k] = (1.0f - 2.0f * yy[k]) * gd[k] * 0.5f;
    t1 += (double)yy[k] * (double)gd[k];
    t2 += (double)yy[k] * (double)bb[k];
  }
  double sy = exp((double)scy[0]) + exp((double)scy[1]) + exp((double)scy[2]) + exp((double)scy[3]);
  __syncthreads();               // all reads of gr_lds (phase D gd init) complete
  *(float4*)&gr_lds[d0] = *(float4*)&scy[0];   // gr_lds now holds sc_y
  double T1 = blockReduce1024(t1, redbuf);
  double T2 = blockReduce1024(t2, redbuf);
  double Tv = blockReduce1024(sy, redbuf);
  if (t == 0) { score_y_s = 0.5 * (T1 + T2); Tsum_s = Tv; }
  __syncthreads();

  // ================= phase E: accept + output =================
  if (t < MAXR) {
    int id = fidx[t];
    scx_s[t] = sc_lds[id];
    scy_s[t] = gr_lds[id];
  }
  __syncthreads();
  if (t < 32) {
    int lane = t;
    double S = Ssum_s, T = Tsum_s;
    double ex = (t < MAXR) ? exp((double)scx_s[t]) : 0.0;
    double scn = ex;
    #pragma unroll
    for (int off = 1; off < 32; off <<= 1) {
      double ov = __shfl_up(scn, off);
      if (lane >= off) scn += ov;
    }
    double pre = scn - ex;
    double gf = (t < nf) ? ((double)scx_s[t] - dlog(S - pre)) : 0.0;
    double ey = (t < MAXR) ? exp((double)scy_s[t]) : 0.0;
    double scn2 = ey;
    #pragma unroll
    for (int off = 1; off < 32; off <<= 1) {
      double ov = __shfl_down(scn2, off);
      if (lane + off < 32) scn2 += ov;
    }
    double suf = scn2 - ey;
    double gb = (t < nf) ? ((double)scy_s[t] - dlog(T - suf)) : 0.0;
    #pragma unroll
    for (int off = 16; off > 0; off >>= 1) {
      gf += __shfl_down(gf, off);
      gb += __shfl_down(gb, off);
    }
    if (t == 0) {
      double log_acc = (gb + score_y_s) - (gf + score_x_s);
      accf = (exp(log_acc) >= (double)uacc_of(b)) ? 1.0f : 0.0f;
    }
  }
  __syncthreads();
  float a = accf;
  float4 ov4;
  ov4.x = a * yy[0] + (1.0f - a) * xx[0];
  ov4.y = a * yy[1] + (1.0f - a) * xx[1];
  ov4.z = a * yy[2] + (1.0f - a) * xx[2];
  ov4.w = a * yy[3] + (1.0f - a) * xx[3];
  *(float4*)&out[o] = ov4;
}

extern "C" void kernel_launch(void* const* d_in, const int* in_sizes, int n_in,
                              void* d_out, int out_size, void* d_ws, size_t ws_size,
                              hipStream_t stream) {
  const float* x    = (const float*)d_in[0];
  const float* W    = (const float*)d_in[1];
  const float* bias = (const float*)d_in[2];
  float* out = (float*)d_out;
  char* ws = (char*)d_ws;
  const size_t MB = 1ull << 20;

  float* Cpart = (float*)ws;                       // KS * 4 MB

  int KS = 1;
  if      (ws_size >= 16*MB) KS = 4;
  else if (ws_size >=  8*MB) KS = 2;

  int NG = 64 * 2 * KS;   // N-tiles x M-tiles x split-K

  k_gemm<<<NG, 256, 0, stream>>>(x, W, Cpart, DD/KS);
  k_tail<<<BB, 1024, 0, stream>>>(Cpart, bias, x, W, out, KS);
}

// Round 9
// 240.276 us; speedup vs baseline: 1.0645x; 1.0645x over previous
//
#include <hip/hip_runtime.h>
#include <math.h>

#define BB 256
#define DD 4096
#define MAXR 31
#define NCAND 4
#define CAPG 192
// filter: u < U_THRESH  =>  g(u) < 3.8 (incl. fp32 rounding slop). GUARD=4.0 check.
#define U_THRESH 0.9778f
#define GUARD 4.0f

typedef unsigned short u16;
typedef u16 u16x8 __attribute__((ext_vector_type(8)));
typedef __bf16 bf16x8 __attribute__((ext_vector_type(8)));
typedef float f32x16 __attribute__((ext_vector_type(16)));

// ---------------- threefry2x32 (JAX schedule), forced v_alignbit rotate ----------------
__device__ __forceinline__ void tf2x32(unsigned k0, unsigned k1, unsigned c0, unsigned c1,
                                       unsigned &o0, unsigned &o1) {
  unsigned ks2 = k0 ^ k1 ^ 0x1BD11BDAu;
  unsigned x0 = c0 + k0;
  unsigned x1 = c1 + k1;
#define TF_R(r) { x0 += x1; x1 = __builtin_rotateleft32(x1, r); x1 ^= x0; }
  TF_R(13) TF_R(15) TF_R(26) TF_R(6)   x0 += k1;  x1 += ks2 + 1u;
  TF_R(17) TF_R(29) TF_R(16) TF_R(24)  x0 += ks2; x1 += k0 + 2u;
  TF_R(13) TF_R(15) TF_R(26) TF_R(6)   x0 += k0;  x1 += k1 + 3u;
  TF_R(17) TF_R(29) TF_R(16) TF_R(24)  x0 += k1;  x1 += ks2 + 4u;
  TF_R(13) TF_R(15) TF_R(26) TF_R(6)   x0 += ks2; x1 += k0 + 5u;
#undef TF_R
  o0 = x0; o1 = x1;
}

__device__ __forceinline__ unsigned tf_xor(unsigned k0, unsigned k1, unsigned c0, unsigned c1) {
  unsigned a, b; tf2x32(k0, k1, c0, c1, a, b); return a ^ b;
}

__device__ __forceinline__ float bits_to_unit(unsigned bits) {
  return __uint_as_float(0x3f800000u | (bits >> 9)) - 1.0f;
}

// sampling key for step j (bit-identical to the original k_rng chain); block-uniform -> SALU
__device__ __forceinline__ void keys_of(int j, unsigned &kk0, unsigned &kk1) {
  unsigned ks0, ks1;
  tf2x32(0u, 42u, 0u, 1u, ks0, ks1);
  tf2x32(ks0, ks1, 0u, (unsigned)j, kk0, kk1);
}

__device__ __forceinline__ int radius_of(int b) {
  unsigned krad0, krad1, k10, k11, k20, k21;
  tf2x32(0u, 42u, 0u, 0u, krad0, krad1);
  tf2x32(krad0, krad1, 0u, 0u, k10, k11);
  tf2x32(krad0, krad1, 0u, 1u, k20, k21);
  unsigned hi = tf_xor(k10, k11, 0u, (unsigned)b);
  unsigned lo = tf_xor(k20, k21, 0u, (unsigned)b);
  return 1 + (int)(((hi % 31u) * 4u + (lo % 31u)) % 31u);
}

__device__ __forceinline__ float uacc_of(int b) {
  unsigned ka0, ka1;
  tf2x32(0u, 42u, 0u, 2u, ka0, ka1);
  return bits_to_unit(tf_xor(ka0, ka1, 0u, (unsigned)b));
}

// ---------------- fast accurate double log (~1e-13 rel) ----------------
__device__ __forceinline__ double dlog(double x) {
  unsigned long long ub = (unsigned long long)__double_as_longlong(x);
  int e = (int)((ub >> 52) & 0x7FFull) - 1022;
  double m = __longlong_as_double((long long)((ub & 0x000FFFFFFFFFFFFFull) | 0x3FE0000000000000ull));
  if (m < 0.70710678118654752440) { m *= 2.0; e -= 1; }
  double r = (m - 1.0) / (m + 1.0);
  double z = r * r;
  double s = fma(z, fma(z, fma(z, fma(z, fma(z, fma(z, 1.0/15.0, 1.0/13.0),
                1.0/11.0), 1.0/9.0), 1.0/7.0), 1.0/5.0), 1.0/3.0);
  double t2 = 2.0 * r;
  return fma((double)e, 0.69314718055994530942, fma(t2 * z, s, t2));
}

// gumbel from uniform u (u>0), fp32-rounded at each log (matches XLA)
__device__ __forceinline__ float gumbel_from_u(float f) {
  float uu = (f == 0.0f) ? 1.17549435e-38f : f;
  float t1 = (float)dlog((double)uu);
  return -(float)dlog((double)(-t1));
}

__device__ __forceinline__ float gumbel_of(unsigned kk0, unsigned kk1, unsigned n) {
  return gumbel_from_u(bits_to_unit(tf_xor(kk0, kk1, 0u, n)));
}

// 1024-thread double reduce (16 waves)
__device__ __forceinline__ double blockReduce1024(double v, double* lds) {
  int t = threadIdx.x;
  #pragma unroll
  for (int off = 32; off > 0; off >>= 1) v += __shfl_down(v, off);
  __syncthreads();
  if ((t & 63) == 0) lds[t >> 6] = v;
  __syncthreads();
  double s = 0.0;
  #pragma unroll
  for (int i = 0; i < 16; i++) s += lds[i];
  return s;
}

// ---------------- W 3-way bf16 split ----------------
__device__ __forceinline__ void split3(float w, u16 &h, u16 &l, u16 &q) {
  __bf16 hb = (__bf16)w;
  float r = w - (float)hb;        // exact
  __bf16 lb = (__bf16)r;
  float r2 = r - (float)lb;       // exact
  __bf16 qb = (__bf16)r2;
  h = __builtin_bit_cast(u16, hb);
  l = __builtin_bit_cast(u16, lb);
  q = __builtin_bit_cast(u16, qb);
}

// ---------------- K_GEMM: pure 128x64-tile bf16 3-split MFMA GEMM ----------------
__global__ __launch_bounds__(256, 2) void k_gemm(
    const float* __restrict__ x, const float* __restrict__ W,
    float* __restrict__ Cpart, int klen) {
  int t = threadIdx.x;
  int g = blockIdx.x;
  int nt = g & 63, mt = (g >> 6) & 1, kc = g >> 7;
  int k0 = kc * klen;

  __shared__ alignas(16) u16 As[4][128][8];     // 8 KB  (x tile bf16)
  __shared__ alignas(16) u16 Bs[3][4][64][8];   // 12 KB (Wh/Wl/Wl2)

  const float* xrow = x + (size_t)(mt * 128) * DD + k0;
  const float* wrow = W + (size_t)(nt * 64) * DD + k0;   // W symmetric: rows give B^T

  int am = t >> 2, akg = t & 3;
  int bn = t >> 2, bkg = t & 3;

  float4 aR0, aR1, aR2, aR3;
  float4 bR0, bR1;
  int nsteps = klen / 32;

  { // prefetch step 0
    const float* ap = xrow + (size_t)am * DD + akg * 8;
    aR0 = *(const float4*)ap;       aR1 = *(const float4*)(ap + 4);
    const float* ap2 = ap + (size_t)64 * DD;
    aR2 = *(const float4*)ap2;      aR3 = *(const float4*)(ap2 + 4);
    const float* wp = wrow + (size_t)bn * DD + bkg * 8;
    bR0 = *(const float4*)wp;       bR1 = *(const float4*)(wp + 4);
  }

  int wid = t >> 6, lane = t & 63;
  int wr = (wid >> 1) * 64, wc = (wid & 1) * 32;
  int lm = lane & 31, lh = lane >> 5;

  f32x16 acc[2];
  #pragma unroll
  for (int i = 0; i < 2; i++)
    #pragma unroll
    for (int r = 0; r < 16; r++) acc[i][r] = 0.0f;

  for (int s = 0; s < nsteps; s++) {
    __syncthreads();
    { // A convert (exact: x in {0,1}) + write
      float af32[8];
      *(float4*)&af32[0] = aR0; *(float4*)&af32[4] = aR1;
      u16x8 av;
      #pragma unroll
      for (int i = 0; i < 8; i++) av[i] = __builtin_bit_cast(u16, (__bf16)af32[i]);
      *(u16x8*)&As[akg][am][0] = av;
      *(float4*)&af32[0] = aR2; *(float4*)&af32[4] = aR3;
      #pragma unroll
      for (int i = 0; i < 8; i++) av[i] = __builtin_bit_cast(u16, (__bf16)af32[i]);
      *(u16x8*)&As[akg][am + 64][0] = av;
    }
    { // B split3 + write 3 planes
      float wv[8];
      *(float4*)&wv[0] = bR0; *(float4*)&wv[4] = bR1;
      u16x8 ph, pl, pq;
      #pragma unroll
      for (int i = 0; i < 8; i++) {
        u16 hh, ll, qq;
        split3(wv[i], hh, ll, qq);
        ph[i] = hh; pl[i] = ll; pq[i] = qq;
      }
      *(u16x8*)&Bs[0][bkg][bn][0] = ph;
      *(u16x8*)&Bs[1][bkg][bn][0] = pl;
      *(u16x8*)&Bs[2][bkg][bn][0] = pq;
    }
    __syncthreads();
    if (s + 1 < nsteps) { // prefetch next step
      int kk = (s + 1) * 32;
      const float* ap = xrow + (size_t)am * DD + kk + akg * 8;
      aR0 = *(const float4*)ap;       aR1 = *(const float4*)(ap + 4);
      const float* ap2 = ap + (size_t)64 * DD;
      aR2 = *(const float4*)ap2;      aR3 = *(const float4*)(ap2 + 4);
      const float* wp = wrow + (size_t)bn * DD + kk + bkg * 8;
      bR0 = *(const float4*)wp;       bR1 = *(const float4*)(wp + 4);
    }
    bf16x8 af[2][2];
    #pragma unroll
    for (int mf = 0; mf < 2; mf++)
      #pragma unroll
      for (int h = 0; h < 2; h++)
        af[mf][h] = *(const bf16x8*)&As[2 * h + lh][wr + mf * 32 + lm][0];
    #pragma unroll
    for (int p = 0; p < 3; p++) {
      bf16x8 b0 = *(const bf16x8*)&Bs[p][lh][wc + lm][0];
      bf16x8 b1 = *(const bf16x8*)&Bs[p][2 + lh][wc + lm][0];
      #pragma unroll
      for (int mf = 0; mf < 2; mf++) {
        acc[mf] = __builtin_amdgcn_mfma_f32_32x32x16_bf16(af[mf][0], b0, acc[mf], 0, 0, 0);
        acc[mf] = __builtin_amdgcn_mfma_f32_32x32x16_bf16(af[mf][1], b1, acc[mf], 0, 0, 0);
      }
    }
  }

  float* Cp = Cpart + (size_t)kc * ((size_t)BB * DD);
  #pragma unroll
  for (int mf = 0; mf < 2; mf++) {
    int col   = nt * 64 + wc + lm;
    int rbase = mt * 128 + wr + mf * 32 + 4 * lh;
    #pragma unroll
    for (int r = 0; r < 16; r++) {
      int row = rbase + (r & 3) + 8 * (r >> 2);
      Cp[(size_t)row * DD + col] = acc[mf][r];
    }
  }
}

// ---------------- K_FILTER: threefry u-filter, tiny LDS -> full occupancy ----------------
__global__ __launch_bounds__(256) void k_filter(
    u16* __restrict__ flt_list, int* __restrict__ flt_cnt) {
  int t = threadIdx.x;
  int fb = blockIdx.x;
  int b = fb / MAXR, j = fb % MAXR;
  unsigned kk0, kk1;
  keys_of(j, kk0, kk1);                 // block-uniform -> SALU
  unsigned base_c = (unsigned)(b * DD);
  // integer threshold: pass <=> bits_to_unit(bits) >= U_THRESH  <=>  (bits>>9) >= KMIN
  const unsigned KMIN = (unsigned)ceil((double)U_THRESH * 8388608.0);

  __shared__ int fcnt;
  __shared__ u16 fl[CAPG];
  if (t == 0) fcnt = 0;
  __syncthreads();

  #pragma unroll
  for (int p = 0; p < 16; p++) {
    int d = t + 256 * p;
    unsigned bits = tf_xor(kk0, kk1, 0u, base_c + (unsigned)d);
    if ((bits >> 9) >= KMIN) {
      int pos = atomicAdd(&fcnt, 1);
      if (pos < CAPG) fl[pos] = (u16)d;
    }
  }
  __syncthreads();
  int n = fcnt;
  if (t == 0) flt_cnt[fb] = n;
  int nstore = n < CAPG ? n : CAPG;
  if (t < nstore) flt_list[(size_t)fb * CAPG + t] = fl[t];
}

// ---------------- K_TAIL: everything after the GEMM, one block per batch row ----------
// phases: A reduce+score  B top4 (one j per wave, butterfly)  (B') exact fallback
//         C chain-select  D y/grad_y/score_y                  E accept+output
__global__ __launch_bounds__(1024) void k_tail(
    const float* __restrict__ Cpart, const float* __restrict__ bias,
    const float* __restrict__ x, const float* __restrict__ W,
    const u16* __restrict__ flt_list, const int* __restrict__ flt_cnt,
    float* __restrict__ out, int KS) {
  int b = blockIdx.x, t = threadIdx.x;

  __shared__ float sc_lds[DD];        // 16 KB: sc_x
  __shared__ float gr_lds[DD];        // 16 KB: grad_x, then sc_y
  __shared__ double redbuf[16];
  __shared__ float lmx[16];
  __shared__ float ls_v[16];
  __shared__ int   ls_i[16];
  __shared__ int   win_i[4];
  __shared__ int   cand_lds[MAXR][NCAND];
  __shared__ int   fb_list[MAXR];
  __shared__ int   nfb_s;
  __shared__ int   fidx[MAXR];
  __shared__ float fsgn[MAXR];
  __shared__ unsigned mask[DD / 32];
  __shared__ int   pick_s;
  __shared__ int   nf_s;
  __shared__ float scmax_s;
  __shared__ double score_x_s, score_y_s, Ssum_s, Tsum_s;
  __shared__ float scx_s[MAXR], scy_s[MAXR];
  __shared__ float accf;

  // ================= phase A: split-K reduce, sc_x, score_x, scmax, S =================
  int d0 = t * 4;
  size_t o = (size_t)b * DD + d0;
  float a0 = 0.f, a1 = 0.f, a2 = 0.f, a3 = 0.f;
  for (int kc = 0; kc < KS; kc++) {
    float4 c = *(const float4*)&Cpart[(size_t)kc * BB * DD + o];
    a0 += c.x; a1 += c.y; a2 += c.z; a3 += c.w;
  }
  float4 bv4 = *(const float4*)&bias[d0];
  float4 xv4 = *(const float4*)&x[o];
  float gg[4] = { a0 + bv4.x, a1 + bv4.y, a2 + bv4.z, a3 + bv4.w };
  float xx[4] = { xv4.x, xv4.y, xv4.z, xv4.w };
  float bb[4] = { bv4.x, bv4.y, bv4.z, bv4.w };
  float scv[4];
  double s1 = 0.0, s2 = 0.0;
  float mx = -INFINITY;
  #pragma unroll
  for (int k = 0; k < 4; k++) {
    scv[k] = (1.0f - 2.0f * xx[k]) * gg[k] * 0.5f;
    mx = fmaxf(mx, scv[k]);
    s1 += (double)xx[k] * (double)gg[k];
    s2 += (double)xx[k] * (double)bb[k];
  }
  *(float4*)&sc_lds[d0] = *(float4*)&scv[0];
  *(float4*)&gr_lds[d0] = *(float4*)&gg[0];
  if (t < 128) mask[t] = 0u;
  if (t == 0) { nf_s = radius_of(b); nfb_s = 0; }
  double sx = exp((double)scv[0]) + exp((double)scv[1]) + exp((double)scv[2]) + exp((double)scv[3]);
  double S1 = blockReduce1024(s1, redbuf);
  double S2 = blockReduce1024(s2, redbuf);
  double Sv = blockReduce1024(sx, redbuf);
  #pragma unroll
  for (int off = 32; off > 0; off >>= 1) mx = fmaxf(mx, __shfl_down(mx, off));
  __syncthreads();
  if ((t & 63) == 0) lmx[t >> 6] = mx;
  __syncthreads();
  if (t == 0) {
    float m = lmx[0];
    #pragma unroll
    for (int i = 1; i < 16; i++) m = fmaxf(m, lmx[i]);
    score_x_s = 0.5 * (S1 + S2);
    scmax_s = m;
    Ssum_s = Sv;
  }
  __syncthreads();

  // ======== phase B: top-4, one j per wave, butterfly reduce (no barriers) ========
  {
    int wv = t >> 6, ln = t & 63;
    float scmax_l = scmax_s;
    for (int pass = 0; pass < 2; pass++) {
      int j = pass * 16 + wv;
      if (j < MAXR) {
        unsigned kk0, kk1;
        keys_of(j, kk0, kk1);
        int n = flt_cnt[b * MAXR + j];
        bool fastok = !(n > CAPG || n < NCAND);
        float v4 = -INFINITY;
        if (fastok) {
          const u16* fl = &flt_list[(size_t)(b * MAXR + j) * CAPG];
          float vv[3]; int dd[3]; unsigned alive = 0u;
          #pragma unroll
          for (int q = 0; q < 3; q++) {
            int idx = ln + 64 * q;
            if (idx < n) {
              int d = (int)fl[idx];
              float f = bits_to_unit(tf_xor(kk0, kk1, 0u, (unsigned)(b * DD) + (unsigned)d));
              vv[q] = sc_lds[d] + gumbel_from_u(f);
              dd[q] = d;
              alive |= 1u << q;
            } else { vv[q] = -INFINITY; dd[q] = 0x7FFFFFFF; }
          }
          for (int r = 0; r < NCAND; r++) {
            float bv = -INFINITY; int bi = 0x7FFFFFFF;
            #pragma unroll
            for (int q = 0; q < 3; q++)
              if (((alive >> q) & 1u) && (vv[q] > bv || (vv[q] == bv && dd[q] < bi))) { bv = vv[q]; bi = dd[q]; }
            #pragma unroll
            for (int off = 1; off < 64; off <<= 1) {
              float ov = __shfl_xor(bv, off);
              int   oi = __shfl_xor(bi, off);
              if (ov > bv || (ov == bv && oi < bi)) { bv = ov; bi = oi; }
            }
            // all 64 lanes agree on (bv, bi)
            if (ln == 0) cand_lds[j][r] = bi;
            v4 = bv;
            #pragma unroll
            for (int q = 0; q < 3; q++) if (dd[q] == bi) alive &= ~(1u << q);
          }
        }
        if (ln == 0) {
          bool needfb = !fastok || (v4 < scmax_l + GUARD);
          if (needfb) fb_list[atomicAdd(&nfb_s, 1)] = j;
        }
      }
    }
  }
  __syncthreads();

  // ================= phase B': exact fallback (statistically ~never) =================
  int nfb = nfb_s;
  for (int fi = 0; fi < nfb; fi++) {
    int j = fb_list[fi];
    unsigned kk0, kk1;
    keys_of(j, kk0, kk1);
    float vq[4]; int dq[4];
    unsigned alive = 0xFu;
    #pragma unroll
    for (int q = 0; q < 4; q++) {
      int d = t * 4 + q;
      vq[q] = sc_lds[d] + gumbel_of(kk0, kk1, (unsigned)(b * DD + d));
      dq[q] = d;
    }
    for (int r = 0; r < NCAND; r++) {
      float lv = -INFINITY; int li = 0x7FFFFFFF;
      #pragma unroll
      for (int q = 0; q < 4; q++)
        if (((alive >> q) & 1u) && (vq[q] > lv || (vq[q] == lv && dq[q] < li))) { lv = vq[q]; li = dq[q]; }
      #pragma unroll
      for (int off = 32; off > 0; off >>= 1) {
        float ov = __shfl_down(lv, off);
        int   oi = __shfl_down(li, off);
        if (ov > lv || (ov == lv && oi < li)) { lv = ov; li = oi; }
      }
      if ((t & 63) == 0) { ls_v[t >> 6] = lv; ls_i[t >> 6] = li; }
      __syncthreads();
      if (t == 0) {
        float fv = ls_v[0]; int fi2 = ls_i[0];
        #pragma unroll
        for (int w = 1; w < 16; w++)
          if (ls_v[w] > fv || (ls_v[w] == fv && ls_i[w] < fi2)) { fv = ls_v[w]; fi2 = ls_i[w]; }
        cand_lds[j][r] = fi2;
        win_i[0] = fi2;
      }
      __syncthreads();
      int wi = win_i[0];
      #pragma unroll
      for (int q = 0; q < 4; q++) if (dq[q] == wi) alive &= ~(1u << q);
    }
    __syncthreads();
  }

  // ================= phase C: blocked-chain resolution =================
  int jdone = 0;
  while (true) {
    if (t == 0) {
      int j = jdone;
      while (j < MAXR) {
        int pick = -1;
        #pragma unroll
        for (int r = 0; r < NCAND; r++) {
          int idx = cand_lds[j][r];
          if (pick < 0 && !((mask[idx >> 5] >> (idx & 31)) & 1u)) pick = idx;
        }
        if (pick < 0) break;
        fidx[j] = pick;
        mask[pick >> 5] |= (1u << (pick & 31));
        j++;
      }
      pick_s = j;
    }
    __syncthreads();
    int jf = pick_s;
    if (jf >= MAXR) break;
    { // cooperative exact fallback for step jf
      unsigned kk0, kk1;
      keys_of(jf, kk0, kk1);
      float lv = -INFINITY; int li = 0x7FFFFFFF;
      #pragma unroll
      for (int q = 0; q < 4; q++) {
        int d = t * 4 + q;
        if ((mask[d >> 5] >> (d & 31)) & 1u) continue;
        float vv = sc_lds[d] + gumbel_of(kk0, kk1, (unsigned)(b * DD + d));
        if (vv > lv || (vv == lv && d < li)) { lv = vv; li = d; }
      }
      #pragma unroll
      for (int off = 32; off > 0; off >>= 1) {
        float ov = __shfl_down(lv, off);
        int   oi = __shfl_down(li, off);
        if (ov > lv || (ov == lv && oi < li)) { lv = ov; li = oi; }
      }
      if ((t & 63) == 0) { ls_v[t >> 6] = lv; ls_i[t >> 6] = li; }
      __syncthreads();
      if (t == 0) {
        float fv = ls_v[0]; int fi2 = ls_i[0];
        #pragma unroll
        for (int w = 1; w < 16; w++)
          if (ls_v[w] > fv || (ls_v[w] == fv && ls_i[w] < fi2)) { fv = ls_v[w]; fi2 = ls_i[w]; }
        fidx[jf] = fi2;
        mask[fi2 >> 5] |= (1u << (fi2 & 31));
      }
      __syncthreads();
    }
    jdone = jf + 1;
  }

  int nf = nf_s;
  if (t < nf) fsgn[t] = 1.0f - 2.0f * x[(size_t)b * DD + fidx[t]];
  __syncthreads();

  // ================= phase D: y, grad_y, sc_y, score_y, T =================
  float gd[4] = { gr_lds[d0], gr_lds[d0 + 1], gr_lds[d0 + 2], gr_lds[d0 + 3] };
  float yy[4] = { xx[0], xx[1], xx[2], xx[3] };
  for (int jj = 0; jj < nf; jj++) {
    int fd = fidx[jj];
    float s = fsgn[jj];
    float4 wv = *(const float4*)&W[(size_t)fd * DD + d0];
    gd[0] = fmaf(s, wv.x, gd[0]);
    gd[1] = fmaf(s, wv.y, gd[1]);
    gd[2] = fmaf(s, wv.z, gd[2]);
    gd[3] = fmaf(s, wv.w, gd[3]);
    int r = fd - d0;
    if (r >= 0 && r < 4) yy[r] = 1.0f - xx[r];
  }
  float scy[4];
  double t1 = 0.0, t2 = 0.0;
  #pragma unroll
  for (int k = 0; k < 4; k++) {
    scy[k] = (1.0f - 2.0f * yy[k]) * gd[k] * 0.5f;
    t1 += (double)yy[k] * (double)gd[k];
    t2 += (double)yy[k] * (double)bb[k];
  }
  double sy = exp((double)scy[0]) + exp((double)scy[1]) + exp((double)scy[2]) + exp((double)scy[3]);
  __syncthreads();               // all reads of gr_lds (phase D gd init) complete
  *(float4*)&gr_lds[d0] = *(float4*)&scy[0];   // gr_lds now holds sc_y
  double T1 = blockReduce1024(t1, redbuf);
  double T2 = blockReduce1024(t2, redbuf);
  double Tv = blockReduce1024(sy, redbuf);
  if (t == 0) { score_y_s = 0.5 * (T1 + T2); Tsum_s = Tv; }
  __syncthreads();

  // ================= phase E: accept + output =================
  if (t < MAXR) {
    int id = fidx[t];
    scx_s[t] = sc_lds[id];
    scy_s[t] = gr_lds[id];
  }
  __syncthreads();
  if (t < 32) {
    int lane = t;
    double S = Ssum_s, T = Tsum_s;
    double ex = (t < MAXR) ? exp((double)scx_s[t]) : 0.0;
    double scn = ex;
    #pragma unroll
    for (int off = 1; off < 32; off <<= 1) {
      double ov = __shfl_up(scn, off);
      if (lane >= off) scn += ov;
    }
    double pre = scn - ex;
    double gf = (t < nf) ? ((double)scx_s[t] - dlog(S - pre)) : 0.0;
    double ey = (t < MAXR) ? exp((double)scy_s[t]) : 0.0;
    double scn2 = ey;
    #pragma unroll
    for (int off = 1; off < 32; off <<= 1) {
      double ov = __shfl_down(scn2, off);
      if (lane + off < 32) scn2 += ov;
    }
    double suf = scn2 - ey;
    double gb = (t < nf) ? ((double)scy_s[t] - dlog(T - suf)) : 0.0;
    #pragma unroll
    for (int off = 16; off > 0; off >>= 1) {
      gf += __shfl_down(gf, off);
      gb += __shfl_down(gb, off);
    }
    if (t == 0) {
      double log_acc = (gb + score_y_s) - (gf + score_x_s);
      accf = (exp(log_acc) >= (double)uacc_of(b)) ? 1.0f : 0.0f;
    }
  }
  __syncthreads();
  float a = accf;
  float4 ov4;
  ov4.x = a * yy[0] + (1.0f - a) * xx[0];
  ov4.y = a * yy[1] + (1.0f - a) * xx[1];
  ov4.z = a * yy[2] + (1.0f - a) * xx[2];
  ov4.w = a * yy[3] + (1.0f - a) * xx[3];
  *(float4*)&out[o] = ov4;
}

extern "C" void kernel_launch(void* const* d_in, const int* in_sizes, int n_in,
                              void* d_out, int out_size, void* d_ws, size_t ws_size,
                              hipStream_t stream) {
  const float* x    = (const float*)d_in[0];
  const float* W    = (const float*)d_in[1];
  const float* bias = (const float*)d_in[2];
  float* out = (float*)d_out;
  char* ws = (char*)d_ws;
  const size_t MB = 1ull << 20;

  u16*    flt_list = (u16*)(ws + 0*MB);             // 7936*192*2 = 2.91 MB
  int*    flt_cnt  = (int*)(ws + 3*MB);             // 32 KB
  float*  Cpart    = (float*)(ws + 4*MB);           // KS * 4 MB

  size_t base = 4*MB;
  int KS = 1;
  if      (ws_size >= base + 16*MB) KS = 4;
  else if (ws_size >= base +  8*MB) KS = 2;

  int NG = 64 * 2 * KS;   // N-tiles x M-tiles x split-K

  k_filter<<<BB*MAXR, 256, 0, stream>>>(flt_list, flt_cnt);
  k_gemm  <<<NG, 256, 0, stream>>>(x, W, Cpart, DD/KS);
  k_tail  <<<BB, 1024, 0, stream>>>(Cpart, bias, x, W, flt_list, flt_cnt, out, KS);
}

// Round 10
// 237.163 us; speedup vs baseline: 1.0785x; 1.0131x over previous
//
#include <hip/hip_runtime.h>
#include <math.h>

#define BB 256
#define DD 4096
#define MAXR 31
#define NCAND 4
#define CAPG 192
// filter: u < U_THRESH  =>  g(u) < 3.8 (incl. fp32 rounding slop). GUARD=4.0 check.
#define U_THRESH 0.9778f
#define GUARD 4.0f

typedef unsigned short u16;
typedef u16 u16x8 __attribute__((ext_vector_type(8)));
typedef __bf16 bf16x8 __attribute__((ext_vector_type(8)));
typedef float f32x16 __attribute__((ext_vector_type(16)));

// ---------------- threefry2x32 (JAX schedule) ----------------
__device__ __forceinline__ void tf2x32(unsigned k0, unsigned k1, unsigned c0, unsigned c1,
                                       unsigned &o0, unsigned &o1) {
  unsigned ks2 = k0 ^ k1 ^ 0x1BD11BDAu;
  unsigned x0 = c0 + k0;
  unsigned x1 = c1 + k1;
#define TF_R(r) { x0 += x1; x1 = __builtin_rotateleft32(x1, r); x1 ^= x0; }
  TF_R(13) TF_R(15) TF_R(26) TF_R(6)   x0 += k1;  x1 += ks2 + 1u;
  TF_R(17) TF_R(29) TF_R(16) TF_R(24)  x0 += ks2; x1 += k0 + 2u;
  TF_R(13) TF_R(15) TF_R(26) TF_R(6)   x0 += k0;  x1 += k1 + 3u;
  TF_R(17) TF_R(29) TF_R(16) TF_R(24)  x0 += k1;  x1 += ks2 + 4u;
  TF_R(13) TF_R(15) TF_R(26) TF_R(6)   x0 += ks2; x1 += k0 + 5u;
#undef TF_R
  o0 = x0; o1 = x1;
}

__device__ __forceinline__ unsigned tf_xor(unsigned k0, unsigned k1, unsigned c0, unsigned c1) {
  unsigned a, b; tf2x32(k0, k1, c0, c1, a, b); return a ^ b;
}

// 4-way interleaved threefry (c0 = 0): 4 independent chains in flight for ILP.
// Bit-identical per-element results; only instruction scheduling differs.
__device__ __forceinline__ void tf_xor_x4(unsigned k0, unsigned k1,
                                          const unsigned c1in[4], unsigned outb[4]) {
  unsigned ks2 = k0 ^ k1 ^ 0x1BD11BDAu;
  unsigned x0[4], x1[4];
  #pragma unroll
  for (int i = 0; i < 4; i++) { x0[i] = k0; x1[i] = c1in[i] + k1; }
#define TF_R4(r) { _Pragma("unroll") for (int i = 0; i < 4; i++) { \
    x0[i] += x1[i]; x1[i] = __builtin_rotateleft32(x1[i], r); x1[i] ^= x0[i]; } }
#define TF_INJ4(a, b) { _Pragma("unroll") for (int i = 0; i < 4; i++) { \
    x0[i] += (a); x1[i] += (b); } }
  TF_R4(13) TF_R4(15) TF_R4(26) TF_R4(6)   TF_INJ4(k1,  ks2 + 1u)
  TF_R4(17) TF_R4(29) TF_R4(16) TF_R4(24)  TF_INJ4(ks2, k0 + 2u)
  TF_R4(13) TF_R4(15) TF_R4(26) TF_R4(6)   TF_INJ4(k0,  k1 + 3u)
  TF_R4(17) TF_R4(29) TF_R4(16) TF_R4(24)  TF_INJ4(k1,  ks2 + 4u)
  TF_R4(13) TF_R4(15) TF_R4(26) TF_R4(6)   TF_INJ4(ks2, k0 + 5u)
#undef TF_R4
#undef TF_INJ4
  #pragma unroll
  for (int i = 0; i < 4; i++) outb[i] = x0[i] ^ x1[i];
}

__device__ __forceinline__ float bits_to_unit(unsigned bits) {
  return __uint_as_float(0x3f800000u | (bits >> 9)) - 1.0f;
}

// sampling key for step j (bit-identical to the original k_rng chain); block-uniform -> SALU
__device__ __forceinline__ void keys_of(int j, unsigned &kk0, unsigned &kk1) {
  unsigned ks0, ks1;
  tf2x32(0u, 42u, 0u, 1u, ks0, ks1);
  tf2x32(ks0, ks1, 0u, (unsigned)j, kk0, kk1);
}

__device__ __forceinline__ int radius_of(int b) {
  unsigned krad0, krad1, k10, k11, k20, k21;
  tf2x32(0u, 42u, 0u, 0u, krad0, krad1);
  tf2x32(krad0, krad1, 0u, 0u, k10, k11);
  tf2x32(krad0, krad1, 0u, 1u, k20, k21);
  unsigned hi = tf_xor(k10, k11, 0u, (unsigned)b);
  unsigned lo = tf_xor(k20, k21, 0u, (unsigned)b);
  return 1 + (int)(((hi % 31u) * 4u + (lo % 31u)) % 31u);
}

__device__ __forceinline__ float uacc_of(int b) {
  unsigned ka0, ka1;
  tf2x32(0u, 42u, 0u, 2u, ka0, ka1);
  return bits_to_unit(tf_xor(ka0, ka1, 0u, (unsigned)b));
}

// ---------------- fast accurate double log (~1e-13 rel) ----------------
__device__ __forceinline__ double dlog(double x) {
  unsigned long long ub = (unsigned long long)__double_as_longlong(x);
  int e = (int)((ub >> 52) & 0x7FFull) - 1022;
  double m = __longlong_as_double((long long)((ub & 0x000FFFFFFFFFFFFFull) | 0x3FE0000000000000ull));
  if (m < 0.70710678118654752440) { m *= 2.0; e -= 1; }
  double r = (m - 1.0) / (m + 1.0);
  double z = r * r;
  double s = fma(z, fma(z, fma(z, fma(z, fma(z, fma(z, 1.0/15.0, 1.0/13.0),
                1.0/11.0), 1.0/9.0), 1.0/7.0), 1.0/5.0), 1.0/3.0);
  double t2 = 2.0 * r;
  return fma((double)e, 0.69314718055994530942, fma(t2 * z, s, t2));
}

// gumbel from uniform u (u>0), fp32-rounded at each log (matches XLA)
__device__ __forceinline__ float gumbel_from_u(float f) {
  float uu = (f == 0.0f) ? 1.17549435e-38f : f;
  float t1 = (float)dlog((double)uu);
  return -(float)dlog((double)(-t1));
}

__device__ __forceinline__ float gumbel_of(unsigned kk0, unsigned kk1, unsigned n) {
  return gumbel_from_u(bits_to_unit(tf_xor(kk0, kk1, 0u, n)));
}

// 1024-thread double reduce (16 waves)
__device__ __forceinline__ double blockReduce1024(double v, double* lds) {
  int t = threadIdx.x;
  #pragma unroll
  for (int off = 32; off > 0; off >>= 1) v += __shfl_down(v, off);
  __syncthreads();
  if ((t & 63) == 0) lds[t >> 6] = v;
  __syncthreads();
  double s = 0.0;
  #pragma unroll
  for (int i = 0; i < 16; i++) s += lds[i];
  return s;
}

// ---------------- W 3-way bf16 split ----------------
__device__ __forceinline__ void split3(float w, u16 &h, u16 &l, u16 &q) {
  __bf16 hb = (__bf16)w;
  float r = w - (float)hb;        // exact
  __bf16 lb = (__bf16)r;
  float r2 = r - (float)lb;       // exact
  __bf16 qb = (__bf16)r2;
  h = __builtin_bit_cast(u16, hb);
  l = __builtin_bit_cast(u16, lb);
  q = __builtin_bit_cast(u16, qb);
}

// ---------------- K_GEMM: pure 128x64-tile bf16 3-split MFMA GEMM ----------------
__global__ __launch_bounds__(256, 2) void k_gemm(
    const float* __restrict__ x, const float* __restrict__ W,
    float* __restrict__ Cpart, int klen) {
  int t = threadIdx.x;
  int g = blockIdx.x;
  int nt = g & 63, mt = (g >> 6) & 1, kc = g >> 7;
  int k0 = kc * klen;

  __shared__ alignas(16) u16 As[4][128][8];     // 8 KB  (x tile bf16)
  __shared__ alignas(16) u16 Bs[3][4][64][8];   // 12 KB (Wh/Wl/Wl2)

  const float* xrow = x + (size_t)(mt * 128) * DD + k0;
  const float* wrow = W + (size_t)(nt * 64) * DD + k0;   // W symmetric: rows give B^T

  int am = t >> 2, akg = t & 3;
  int bn = t >> 2, bkg = t & 3;

  float4 aR0, aR1, aR2, aR3;
  float4 bR0, bR1;
  int nsteps = klen / 32;

  { // prefetch step 0
    const float* ap = xrow + (size_t)am * DD + akg * 8;
    aR0 = *(const float4*)ap;       aR1 = *(const float4*)(ap + 4);
    const float* ap2 = ap + (size_t)64 * DD;
    aR2 = *(const float4*)ap2;      aR3 = *(const float4*)(ap2 + 4);
    const float* wp = wrow + (size_t)bn * DD + bkg * 8;
    bR0 = *(const float4*)wp;       bR1 = *(const float4*)(wp + 4);
  }

  int wid = t >> 6, lane = t & 63;
  int wr = (wid >> 1) * 64, wc = (wid & 1) * 32;
  int lm = lane & 31, lh = lane >> 5;

  f32x16 acc[2];
  #pragma unroll
  for (int i = 0; i < 2; i++)
    #pragma unroll
    for (int r = 0; r < 16; r++) acc[i][r] = 0.0f;

  for (int s = 0; s < nsteps; s++) {
    __syncthreads();
    { // A convert (exact: x in {0,1}) + write
      float af32[8];
      *(float4*)&af32[0] = aR0; *(float4*)&af32[4] = aR1;
      u16x8 av;
      #pragma unroll
      for (int i = 0; i < 8; i++) av[i] = __builtin_bit_cast(u16, (__bf16)af32[i]);
      *(u16x8*)&As[akg][am][0] = av;
      *(float4*)&af32[0] = aR2; *(float4*)&af32[4] = aR3;
      #pragma unroll
      for (int i = 0; i < 8; i++) av[i] = __builtin_bit_cast(u16, (__bf16)af32[i]);
      *(u16x8*)&As[akg][am + 64][0] = av;
    }
    { // B split3 + write 3 planes
      float wv[8];
      *(float4*)&wv[0] = bR0; *(float4*)&wv[4] = bR1;
      u16x8 ph, pl, pq;
      #pragma unroll
      for (int i = 0; i < 8; i++) {
        u16 hh, ll, qq;
        split3(wv[i], hh, ll, qq);
        ph[i] = hh; pl[i] = ll; pq[i] = qq;
      }
      *(u16x8*)&Bs[0][bkg][bn][0] = ph;
      *(u16x8*)&Bs[1][bkg][bn][0] = pl;
      *(u16x8*)&Bs[2][bkg][bn][0] = pq;
    }
    __syncthreads();
    if (s + 1 < nsteps) { // prefetch next step
      int kk = (s + 1) * 32;
      const float* ap = xrow + (size_t)am * DD + kk + akg * 8;
      aR0 = *(const float4*)ap;       aR1 = *(const float4*)(ap + 4);
      const float* ap2 = ap + (size_t)64 * DD;
      aR2 = *(const float4*)ap2;      aR3 = *(const float4*)(ap2 + 4);
      const float* wp = wrow + (size_t)bn * DD + kk + bkg * 8;
      bR0 = *(const float4*)wp;       bR1 = *(const float4*)(wp + 4);
    }
    bf16x8 af[2][2];
    #pragma unroll
    for (int mf = 0; mf < 2; mf++)
      #pragma unroll
      for (int h = 0; h < 2; h++)
        af[mf][h] = *(const bf16x8*)&As[2 * h + lh][wr + mf * 32 + lm][0];
    #pragma unroll
    for (int p = 0; p < 3; p++) {
      bf16x8 b0 = *(const bf16x8*)&Bs[p][lh][wc + lm][0];
      bf16x8 b1 = *(const bf16x8*)&Bs[p][2 + lh][wc + lm][0];
      #pragma unroll
      for (int mf = 0; mf < 2; mf++) {
        acc[mf] = __builtin_amdgcn_mfma_f32_32x32x16_bf16(af[mf][0], b0, acc[mf], 0, 0, 0);
        acc[mf] = __builtin_amdgcn_mfma_f32_32x32x16_bf16(af[mf][1], b1, acc[mf], 0, 0, 0);
      }
    }
  }

  float* Cp = Cpart + (size_t)kc * ((size_t)BB * DD);
  #pragma unroll
  for (int mf = 0; mf < 2; mf++) {
    int col   = nt * 64 + wc + lm;
    int rbase = mt * 128 + wr + mf * 32 + 4 * lh;
    #pragma unroll
    for (int r = 0; r < 16; r++) {
      int row = rbase + (r & 3) + 8 * (r >> 2);
      Cp[(size_t)row * DD + col] = acc[mf][r];
    }
  }
}

// ---------------- K_FILTER: threefry u-filter, 4-way ILP hash chains ----------------
__global__ __launch_bounds__(256) void k_filter(
    u16* __restrict__ flt_list, int* __restrict__ flt_cnt) {
  int t = threadIdx.x;
  int fb = blockIdx.x;
  int b = fb / MAXR, j = fb % MAXR;
  unsigned kk0, kk1;
  keys_of(j, kk0, kk1);                 // block-uniform -> SALU
  unsigned base_c = (unsigned)(b * DD);
  // integer threshold: pass <=> bits_to_unit(bits) >= U_THRESH  <=>  (bits>>9) >= KMIN
  const unsigned KMIN = (unsigned)ceil((double)U_THRESH * 8388608.0);

  __shared__ int fcnt;
  __shared__ u16 fl[CAPG];
  if (t == 0) fcnt = 0;
  __syncthreads();

  #pragma unroll
  for (int p = 0; p < 4; p++) {
    unsigned c1[4], bits[4];
    #pragma unroll
    for (int q = 0; q < 4; q++) c1[q] = base_c + (unsigned)(t + 256 * (4 * p + q));
    tf_xor_x4(kk0, kk1, c1, bits);      // 4 independent chains in flight
    #pragma unroll
    for (int q = 0; q < 4; q++) {
      if ((bits[q] >> 9) >= KMIN) {
        int pos = atomicAdd(&fcnt, 1);
        if (pos < CAPG) fl[pos] = (u16)(t + 256 * (4 * p + q));
      }
    }
  }
  __syncthreads();
  int n = fcnt;
  if (t == 0) flt_cnt[fb] = n;
  int nstore = n < CAPG ? n : CAPG;
  if (t < nstore) flt_list[(size_t)fb * CAPG + t] = fl[t];
}

// ---------------- K_TAIL: everything after the GEMM, one block per batch row ----------
// phases: A reduce+score  B top4 (one j per wave, butterfly)  (B') exact fallback
//         C chain-select  D y/grad_y/score_y                  E accept+output
__global__ __launch_bounds__(1024) void k_tail(
    const float* __restrict__ Cpart, const float* __restrict__ bias,
    const float* __restrict__ x, const float* __restrict__ W,
    const u16* __restrict__ flt_list, const int* __restrict__ flt_cnt,
    float* __restrict__ out, int KS) {
  int b = blockIdx.x, t = threadIdx.x;

  __shared__ float sc_lds[DD];        // 16 KB: sc_x
  __shared__ float gr_lds[DD];        // 16 KB: grad_x, then sc_y
  __shared__ double redbuf[16];
  __shared__ float lmx[16];
  __shared__ float ls_v[16];
  __shared__ int   ls_i[16];
  __shared__ int   win_i[4];
  __shared__ int   cand_lds[MAXR][NCAND];
  __shared__ int   fb_list[MAXR];
  __shared__ int   nfb_s;
  __shared__ int   fidx[MAXR];
  __shared__ float fsgn[MAXR];
  __shared__ unsigned mask[DD / 32];
  __shared__ int   pick_s;
  __shared__ int   nf_s;
  __shared__ float scmax_s;
  __shared__ double score_x_s, score_y_s, Ssum_s, Tsum_s;
  __shared__ float scx_s[MAXR], scy_s[MAXR];
  __shared__ float accf;

  // ================= phase A: split-K reduce, sc_x, score_x, scmax, S =================
  int d0 = t * 4;
  size_t o = (size_t)b * DD + d0;
  float a0 = 0.f, a1 = 0.f, a2 = 0.f, a3 = 0.f;
  for (int kc = 0; kc < KS; kc++) {
    float4 c = *(const float4*)&Cpart[(size_t)kc * BB * DD + o];
    a0 += c.x; a1 += c.y; a2 += c.z; a3 += c.w;
  }
  float4 bv4 = *(const float4*)&bias[d0];
  float4 xv4 = *(const float4*)&x[o];
  float gg[4] = { a0 + bv4.x, a1 + bv4.y, a2 + bv4.z, a3 + bv4.w };
  float xx[4] = { xv4.x, xv4.y, xv4.z, xv4.w };
  float bb[4] = { bv4.x, bv4.y, bv4.z, bv4.w };
  float scv[4];
  double s1 = 0.0, s2 = 0.0;
  float mx = -INFINITY;
  #pragma unroll
  for (int k = 0; k < 4; k++) {
    scv[k] = (1.0f - 2.0f * xx[k]) * gg[k] * 0.5f;
    mx = fmaxf(mx, scv[k]);
    s1 += (double)xx[k] * (double)gg[k];
    s2 += (double)xx[k] * (double)bb[k];
  }
  *(float4*)&sc_lds[d0] = *(float4*)&scv[0];
  *(float4*)&gr_lds[d0] = *(float4*)&gg[0];
  if (t < 128) mask[t] = 0u;
  if (t == 0) { nf_s = radius_of(b); nfb_s = 0; }
  double sx = exp((double)scv[0]) + exp((double)scv[1]) + exp((double)scv[2]) + exp((double)scv[3]);
  double S1 = blockReduce1024(s1, redbuf);
  double S2 = blockReduce1024(s2, redbuf);
  double Sv = blockReduce1024(sx, redbuf);
  #pragma unroll
  for (int off = 32; off > 0; off >>= 1) mx = fmaxf(mx, __shfl_down(mx, off));
  __syncthreads();
  if ((t & 63) == 0) lmx[t >> 6] = mx;
  __syncthreads();
  if (t == 0) {
    float m = lmx[0];
    #pragma unroll
    for (int i = 1; i < 16; i++) m = fmaxf(m, lmx[i]);
    score_x_s = 0.5 * (S1 + S2);
    scmax_s = m;
    Ssum_s = Sv;
  }
  __syncthreads();

  // ======== phase B: top-4, one j per wave, butterfly reduce (no barriers) ========
  {
    int wv = t >> 6, ln = t & 63;
    float scmax_l = scmax_s;
    for (int pass = 0; pass < 2; pass++) {
      int j = pass * 16 + wv;
      if (j < MAXR) {
        unsigned kk0, kk1;
        keys_of(j, kk0, kk1);
        int n = flt_cnt[b * MAXR + j];
        bool fastok = !(n > CAPG || n < NCAND);
        float v4 = -INFINITY;
        if (fastok) {
          const u16* fl = &flt_list[(size_t)(b * MAXR + j) * CAPG];
          float vv[3]; int dd[3]; unsigned alive = 0u;
          #pragma unroll
          for (int q = 0; q < 3; q++) {
            int idx = ln + 64 * q;
            if (idx < n) {
              int d = (int)fl[idx];
              float f = bits_to_unit(tf_xor(kk0, kk1, 0u, (unsigned)(b * DD) + (unsigned)d));
              vv[q] = sc_lds[d] + gumbel_from_u(f);
              dd[q] = d;
              alive |= 1u << q;
            } else { vv[q] = -INFINITY; dd[q] = 0x7FFFFFFF; }
          }
          for (int r = 0; r < NCAND; r++) {
            float bv = -INFINITY; int bi = 0x7FFFFFFF;
            #pragma unroll
            for (int q = 0; q < 3; q++)
              if (((alive >> q) & 1u) && (vv[q] > bv || (vv[q] == bv && dd[q] < bi))) { bv = vv[q]; bi = dd[q]; }
            #pragma unroll
            for (int off = 1; off < 64; off <<= 1) {
              float ov = __shfl_xor(bv, off);
              int   oi = __shfl_xor(bi, off);
              if (ov > bv || (ov == bv && oi < bi)) { bv = ov; bi = oi; }
            }
            // all 64 lanes agree on (bv, bi)
            if (ln == 0) cand_lds[j][r] = bi;
            v4 = bv;
            #pragma unroll
            for (int q = 0; q < 3; q++) if (dd[q] == bi) alive &= ~(1u << q);
          }
        }
        if (ln == 0) {
          bool needfb = !fastok || (v4 < scmax_l + GUARD);
          if (needfb) fb_list[atomicAdd(&nfb_s, 1)] = j;
        }
      }
    }
  }
  __syncthreads();

  // ================= phase B': exact fallback (statistically ~never) =================
  int nfb = nfb_s;
  for (int fi = 0; fi < nfb; fi++) {
    int j = fb_list[fi];
    unsigned kk0, kk1;
    keys_of(j, kk0, kk1);
    float vq[4]; int dq[4];
    unsigned alive = 0xFu;
    #pragma unroll
    for (int q = 0; q < 4; q++) {
      int d = t * 4 + q;
      vq[q] = sc_lds[d] + gumbel_of(kk0, kk1, (unsigned)(b * DD + d));
      dq[q] = d;
    }
    for (int r = 0; r < NCAND; r++) {
      float lv = -INFINITY; int li = 0x7FFFFFFF;
      #pragma unroll
      for (int q = 0; q < 4; q++)
        if (((alive >> q) & 1u) && (vq[q] > lv || (vq[q] == lv && dq[q] < li))) { lv = vq[q]; li = dq[q]; }
      #pragma unroll
      for (int off = 32; off > 0; off >>= 1) {
        float ov = __shfl_down(lv, off);
        int   oi = __shfl_down(li, off);
        if (ov > lv || (ov == lv && oi < li)) { lv = ov; li = oi; }
      }
      if ((t & 63) == 0) { ls_v[t >> 6] = lv; ls_i[t >> 6] = li; }
      __syncthreads();
      if (t == 0) {
        float fv = ls_v[0]; int fi2 = ls_i[0];
        #pragma unroll
        for (int w = 1; w < 16; w++)
          if (ls_v[w] > fv || (ls_v[w] == fv && ls_i[w] < fi2)) { fv = ls_v[w]; fi2 = ls_i[w]; }
        cand_lds[j][r] = fi2;
        win_i[0] = fi2;
      }
      __syncthreads();
      int wi = win_i[0];
      #pragma unroll
      for (int q = 0; q < 4; q++) if (dq[q] == wi) alive &= ~(1u << q);
    }
    __syncthreads();
  }

  // ================= phase C: blocked-chain resolution =================
  int jdone = 0;
  while (true) {
    if (t == 0) {
      int j = jdone;
      while (j < MAXR) {
        int pick = -1;
        #pragma unroll
        for (int r = 0; r < NCAND; r++) {
          int idx = cand_lds[j][r];
          if (pick < 0 && !((mask[idx >> 5] >> (idx & 31)) & 1u)) pick = idx;
        }
        if (pick < 0) break;
        fidx[j] = pick;
        mask[pick >> 5] |= (1u << (pick & 31));
        j++;
      }
      pick_s = j;
    }
    __syncthreads();
    int jf = pick_s;
    if (jf >= MAXR) break;
    { // cooperative exact fallback for step jf
      unsigned kk0, kk1;
      keys_of(jf, kk0, kk1);
      float lv = -INFINITY; int li = 0x7FFFFFFF;
      #pragma unroll
      for (int q = 0; q < 4; q++) {
        int d = t * 4 + q;
        if ((mask[d >> 5] >> (d & 31)) & 1u) continue;
        float vv = sc_lds[d] + gumbel_of(kk0, kk1, (unsigned)(b * DD + d));
        if (vv > lv || (vv == lv && d < li)) { lv = vv; li = d; }
      }
      #pragma unroll
      for (int off = 32; off > 0; off >>= 1) {
        float ov = __shfl_down(lv, off);
        int   oi = __shfl_down(li, off);
        if (ov > lv || (ov == lv && oi < li)) { lv = ov; li = oi; }
      }
      if ((t & 63) == 0) { ls_v[t >> 6] = lv; ls_i[t >> 6] = li; }
      __syncthreads();
      if (t == 0) {
        float fv = ls_v[0]; int fi2 = ls_i[0];
        #pragma unroll
        for (int w = 1; w < 16; w++)
          if (ls_v[w] > fv || (ls_v[w] == fv && ls_i[w] < fi2)) { fv = ls_v[w]; fi2 = ls_i[w]; }
        fidx[jf] = fi2;
        mask[fi2 >> 5] |= (1u << (fi2 & 31));
      }
      __syncthreads();
    }
    jdone = jf + 1;
  }

  int nf = nf_s;
  if (t < nf) fsgn[t] = 1.0f - 2.0f * x[(size_t)b * DD + fidx[t]];
  __syncthreads();

  // ================= phase D: y, grad_y, sc_y, score_y, T =================
  float gd[4] = { gr_lds[d0], gr_lds[d0 + 1], gr_lds[d0 + 2], gr_lds[d0 + 3] };
  float yy[4] = { xx[0], xx[1], xx[2], xx[3] };
  for (int jj = 0; jj < nf; jj++) {
    int fd = fidx[jj];
    float s = fsgn[jj];
    float4 wv = *(const float4*)&W[(size_t)fd * DD + d0];
    gd[0] = fmaf(s, wv.x, gd[0]);
    gd[1] = fmaf(s, wv.y, gd[1]);
    gd[2] = fmaf(s, wv.z, gd[2]);
    gd[3] = fmaf(s, wv.w, gd[3]);
    int r = fd - d0;
    if (r >= 0 && r < 4) yy[r] = 1.0f - xx[r];
  }
  float scy[4];
  double t1 = 0.0, t2 = 0.0;
  #pragma unroll
  for (int k = 0; k < 4; k++) {
    scy[k] = (1.0f - 2.0f * yy[k]) * gd[k] * 0.5f;
    t1 += (double)yy[k] * (double)gd[k];
    t2 += (double)yy[k] * (double)bb[k];
  }
  double sy = exp((double)scy[0]) + exp((double)scy[1]) + exp((double)scy[2]) + exp((double)scy[3]);
  __syncthreads();               // all reads of gr_lds (phase D gd init) complete
  *(float4*)&gr_lds[d0] = *(float4*)&scy[0];   // gr_lds now holds sc_y
  double T1 = blockReduce1024(t1, redbuf);
  double T2 = blockReduce1024(t2, redbuf);
  double Tv = blockReduce1024(sy, redbuf);
  if (t == 0) { score_y_s = 0.5 * (T1 + T2); Tsum_s = Tv; }
  __syncthreads();

  // ================= phase E: accept + output =================
  if (t < MAXR) {
    int id = fidx[t];
    scx_s[t] = sc_lds[id];
    scy_s[t] = gr_lds[id];
  }
  __syncthreads();
  if (t < 32) {
    int lane = t;
    double S = Ssum_s, T = Tsum_s;
    double ex = (t < MAXR) ? exp((double)scx_s[t]) : 0.0;
    double scn = ex;
    #pragma unroll
    for (int off = 1; off < 32; off <<= 1) {
      double ov = __shfl_up(scn, off);
      if (lane >= off) scn += ov;
    }
    double pre = scn - ex;
    double gf = (t < nf) ? ((double)scx_s[t] - dlog(S - pre)) : 0.0;
    double ey = (t < MAXR) ? exp((double)scy_s[t]) : 0.0;
    double scn2 = ey;
    #pragma unroll
    for (int off = 1; off < 32; off <<= 1) {
      double ov = __shfl_down(scn2, off);
      if (lane + off < 32) scn2 += ov;
    }
    double suf = scn2 - ey;
    double gb = (t < nf) ? ((double)scy_s[t] - dlog(T - suf)) : 0.0;
    #pragma unroll
    for (int off = 16; off > 0; off >>= 1) {
      gf += __shfl_down(gf, off);
      gb += __shfl_down(gb, off);
    }
    if (t == 0) {
      double log_acc = (gb + score_y_s) - (gf + score_x_s);
      accf = (exp(log_acc) >= (double)uacc_of(b)) ? 1.0f : 0.0f;
    }
  }
  __syncthreads();
  float a = accf;
  float4 ov4;
  ov4.x = a * yy[0] + (1.0f - a) * xx[0];
  ov4.y = a * yy[1] + (1.0f - a) * xx[1];
  ov4.z = a * yy[2] + (1.0f - a) * xx[2];
  ov4.w = a * yy[3] + (1.0f - a) * xx[3];
  *(float4*)&out[o] = ov4;
}

extern "C" void kernel_launch(void* const* d_in, const int* in_sizes, int n_in,
                              void* d_out, int out_size, void* d_ws, size_t ws_size,
                              hipStream_t stream) {
  const float* x    = (const float*)d_in[0];
  const float* W    = (const float*)d_in[1];
  const float* bias = (const float*)d_in[2];
  float* out = (float*)d_out;
  char* ws = (char*)d_ws;
  const size_t MB = 1ull << 20;

  u16*    flt_list = (u16*)(ws + 0*MB);             // 7936*192*2 = 2.91 MB
  int*    flt_cnt  = (int*)(ws + 3*MB);             // 32 KB
  float*  Cpart    = (float*)(ws + 4*MB);           // KS * 4 MB

  size_t base = 4*MB;
  int KS = 1;
  if      (ws_size >= base + 16*MB) KS = 4;
  else if (ws_size >= base +  8*MB) KS = 2;

  int NG = 64 * 2 * KS;   // N-tiles x M-tiles x split-K

  k_filter<<<BB*MAXR, 256, 0, stream>>>(flt_list, flt_cnt);
  k_gemm  <<<NG, 256, 0, stream>>>(x, W, Cpart, DD/KS);
  k_tail  <<<BB, 1024, 0, stream>>>(Cpart, bias, x, W, flt_list, flt_cnt, out, KS);
}

// Round 11
// 236.813 us; speedup vs baseline: 1.0801x; 1.0015x over previous
//
#include <hip/hip_runtime.h>
#include <math.h>

#define BB 256
#define DD 4096
#define MAXR 31
#define NCAND 4
#define CAPG 192
// filter: u < U_THRESH  =>  g(u) < 3.8 (incl. fp32 rounding slop). GUARD=4.0 check.
#define U_THRESH 0.9778f
#define GUARD 4.0f

typedef unsigned short u16;
typedef u16 u16x8 __attribute__((ext_vector_type(8)));
typedef __bf16 bf16x8 __attribute__((ext_vector_type(8)));
typedef float f32x16 __attribute__((ext_vector_type(16)));

// ---------------- threefry2x32 (JAX schedule) ----------------
__device__ __forceinline__ void tf2x32(unsigned k0, unsigned k1, unsigned c0, unsigned c1,
                                       unsigned &o0, unsigned &o1) {
  unsigned ks2 = k0 ^ k1 ^ 0x1BD11BDAu;
  unsigned x0 = c0 + k0;
  unsigned x1 = c1 + k1;
#define TF_R(r) { x0 += x1; x1 = __builtin_rotateleft32(x1, r); x1 ^= x0; }
  TF_R(13) TF_R(15) TF_R(26) TF_R(6)   x0 += k1;  x1 += ks2 + 1u;
  TF_R(17) TF_R(29) TF_R(16) TF_R(24)  x0 += ks2; x1 += k0 + 2u;
  TF_R(13) TF_R(15) TF_R(26) TF_R(6)   x0 += k0;  x1 += k1 + 3u;
  TF_R(17) TF_R(29) TF_R(16) TF_R(24)  x0 += k1;  x1 += ks2 + 4u;
  TF_R(13) TF_R(15) TF_R(26) TF_R(6)   x0 += ks2; x1 += k0 + 5u;
#undef TF_R
  o0 = x0; o1 = x1;
}

__device__ __forceinline__ unsigned tf_xor(unsigned k0, unsigned k1, unsigned c0, unsigned c1) {
  unsigned a, b; tf2x32(k0, k1, c0, c1, a, b); return a ^ b;
}

// 4-way interleaved threefry (c0 = 0): 4 independent chains, FORCED live via empty
// asm pins after every round so the scheduler cannot re-serialize (r10: VGPR=8 proved
// the array version was serialized). Bit-identical per-element results.
__device__ __forceinline__ void tf_xor_x4(unsigned k0, unsigned k1,
                                          const unsigned c1in[4], unsigned outb[4]) {
  unsigned ks2 = k0 ^ k1 ^ 0x1BD11BDAu;
  unsigned a0 = k0, a1 = k0, a2 = k0, a3 = k0;
  unsigned b0 = c1in[0] + k1, b1 = c1in[1] + k1, b2 = c1in[2] + k1, b3 = c1in[3] + k1;
#define PIN4 asm volatile("" : "+v"(a0), "+v"(b0), "+v"(a1), "+v"(b1), \
                               "+v"(a2), "+v"(b2), "+v"(a3), "+v"(b3))
#define R4(r) { a0 += b0; b0 = __builtin_rotateleft32(b0, r); b0 ^= a0; \
                a1 += b1; b1 = __builtin_rotateleft32(b1, r); b1 ^= a1; \
                a2 += b2; b2 = __builtin_rotateleft32(b2, r); b2 ^= a2; \
                a3 += b3; b3 = __builtin_rotateleft32(b3, r); b3 ^= a3; PIN4; }
#define INJ4(p, q) { a0 += (p); b0 += (q); a1 += (p); b1 += (q); \
                     a2 += (p); b2 += (q); a3 += (p); b3 += (q); }
  PIN4;
  R4(13) R4(15) R4(26) R4(6)   INJ4(k1,  ks2 + 1u)
  R4(17) R4(29) R4(16) R4(24)  INJ4(ks2, k0 + 2u)
  R4(13) R4(15) R4(26) R4(6)   INJ4(k0,  k1 + 3u)
  R4(17) R4(29) R4(16) R4(24)  INJ4(k1,  ks2 + 4u)
  R4(13) R4(15) R4(26) R4(6)   INJ4(ks2, k0 + 5u)
  outb[0] = a0 ^ b0; outb[1] = a1 ^ b1; outb[2] = a2 ^ b2; outb[3] = a3 ^ b3;
#undef R4
#undef INJ4
#undef PIN4
}

__device__ __forceinline__ float bits_to_unit(unsigned bits) {
  return __uint_as_float(0x3f800000u | (bits >> 9)) - 1.0f;
}

// sampling key for step j (bit-identical to the original k_rng chain); block-uniform -> SALU
__device__ __forceinline__ void keys_of(int j, unsigned &kk0, unsigned &kk1) {
  unsigned ks0, ks1;
  tf2x32(0u, 42u, 0u, 1u, ks0, ks1);
  tf2x32(ks0, ks1, 0u, (unsigned)j, kk0, kk1);
}

__device__ __forceinline__ int radius_of(int b) {
  unsigned krad0, krad1, k10, k11, k20, k21;
  tf2x32(0u, 42u, 0u, 0u, krad0, krad1);
  tf2x32(krad0, krad1, 0u, 0u, k10, k11);
  tf2x32(krad0, krad1, 0u, 1u, k20, k21);
  unsigned hi = tf_xor(k10, k11, 0u, (unsigned)b);
  unsigned lo = tf_xor(k20, k21, 0u, (unsigned)b);
  return 1 + (int)(((hi % 31u) * 4u + (lo % 31u)) % 31u);
}

__device__ __forceinline__ float uacc_of(int b) {
  unsigned ka0, ka1;
  tf2x32(0u, 42u, 0u, 2u, ka0, ka1);
  return bits_to_unit(tf_xor(ka0, ka1, 0u, (unsigned)b));
}

// ---------------- fast accurate double log (~1e-13 rel) ----------------
__device__ __forceinline__ double dlog(double x) {
  unsigned long long ub = (unsigned long long)__double_as_longlong(x);
  int e = (int)((ub >> 52) & 0x7FFull) - 1022;
  double m = __longlong_as_double((long long)((ub & 0x000FFFFFFFFFFFFFull) | 0x3FE0000000000000ull));
  if (m < 0.70710678118654752440) { m *= 2.0; e -= 1; }
  double r = (m - 1.0) / (m + 1.0);
  double z = r * r;
  double s = fma(z, fma(z, fma(z, fma(z, fma(z, fma(z, 1.0/15.0, 1.0/13.0),
                1.0/11.0), 1.0/9.0), 1.0/7.0), 1.0/5.0), 1.0/3.0);
  double t2 = 2.0 * r;
  return fma((double)e, 0.69314718055994530942, fma(t2 * z, s, t2));
}

// gumbel from uniform u (u>0), fp32-rounded at each log (matches XLA)
__device__ __forceinline__ float gumbel_from_u(float f) {
  float uu = (f == 0.0f) ? 1.17549435e-38f : f;
  float t1 = (float)dlog((double)uu);
  return -(float)dlog((double)(-t1));
}

__device__ __forceinline__ float gumbel_of(unsigned kk0, unsigned kk1, unsigned n) {
  return gumbel_from_u(bits_to_unit(tf_xor(kk0, kk1, 0u, n)));
}

// 1024-thread double reduce (16 waves)
__device__ __forceinline__ double blockReduce1024(double v, double* lds) {
  int t = threadIdx.x;
  #pragma unroll
  for (int off = 32; off > 0; off >>= 1) v += __shfl_down(v, off);
  __syncthreads();
  if ((t & 63) == 0) lds[t >> 6] = v;
  __syncthreads();
  double s = 0.0;
  #pragma unroll
  for (int i = 0; i < 16; i++) s += lds[i];
  return s;
}

// ---------------- W 3-way bf16 split ----------------
__device__ __forceinline__ void split3(float w, u16 &h, u16 &l, u16 &q) {
  __bf16 hb = (__bf16)w;
  float r = w - (float)hb;        // exact
  __bf16 lb = (__bf16)r;
  float r2 = r - (float)lb;       // exact
  __bf16 qb = (__bf16)r2;
  h = __builtin_bit_cast(u16, hb);
  l = __builtin_bit_cast(u16, lb);
  q = __builtin_bit_cast(u16, qb);
}

// ---------------- K_GEMM: pure 128x64-tile bf16 3-split MFMA GEMM ----------------
__global__ __launch_bounds__(256, 2) void k_gemm(
    const float* __restrict__ x, const float* __restrict__ W,
    float* __restrict__ Cpart, int klen) {
  int t = threadIdx.x;
  int g = blockIdx.x;
  int nt = g & 63, mt = (g >> 6) & 1, kc = g >> 7;
  int k0 = kc * klen;

  __shared__ alignas(16) u16 As[4][128][8];     // 8 KB  (x tile bf16)
  __shared__ alignas(16) u16 Bs[3][4][64][8];   // 12 KB (Wh/Wl/Wl2)

  const float* xrow = x + (size_t)(mt * 128) * DD + k0;
  const float* wrow = W + (size_t)(nt * 64) * DD + k0;   // W symmetric: rows give B^T

  int am = t >> 2, akg = t & 3;
  int bn = t >> 2, bkg = t & 3;

  float4 aR0, aR1, aR2, aR3;
  float4 bR0, bR1;
  int nsteps = klen / 32;

  { // prefetch step 0
    const float* ap = xrow + (size_t)am * DD + akg * 8;
    aR0 = *(const float4*)ap;       aR1 = *(const float4*)(ap + 4);
    const float* ap2 = ap + (size_t)64 * DD;
    aR2 = *(const float4*)ap2;      aR3 = *(const float4*)(ap2 + 4);
    const float* wp = wrow + (size_t)bn * DD + bkg * 8;
    bR0 = *(const float4*)wp;       bR1 = *(const float4*)(wp + 4);
  }

  int wid = t >> 6, lane = t & 63;
  int wr = (wid >> 1) * 64, wc = (wid & 1) * 32;
  int lm = lane & 31, lh = lane >> 5;

  f32x16 acc[2];
  #pragma unroll
  for (int i = 0; i < 2; i++)
    #pragma unroll
    for (int r = 0; r < 16; r++) acc[i][r] = 0.0f;

  for (int s = 0; s < nsteps; s++) {
    __syncthreads();
    { // A convert (exact: x in {0,1}) + write
      float af32[8];
      *(float4*)&af32[0] = aR0; *(float4*)&af32[4] = aR1;
      u16x8 av;
      #pragma unroll
      for (int i = 0; i < 8; i++) av[i] = __builtin_bit_cast(u16, (__bf16)af32[i]);
      *(u16x8*)&As[akg][am][0] = av;
      *(float4*)&af32[0] = aR2; *(float4*)&af32[4] = aR3;
      #pragma unroll
      for (int i = 0; i < 8; i++) av[i] = __builtin_bit_cast(u16, (__bf16)af32[i]);
      *(u16x8*)&As[akg][am + 64][0] = av;
    }
    { // B split3 + write 3 planes
      float wv[8];
      *(float4*)&wv[0] = bR0; *(float4*)&wv[4] = bR1;
      u16x8 ph, pl, pq;
      #pragma unroll
      for (int i = 0; i < 8; i++) {
        u16 hh, ll, qq;
        split3(wv[i], hh, ll, qq);
        ph[i] = hh; pl[i] = ll; pq[i] = qq;
      }
      *(u16x8*)&Bs[0][bkg][bn][0] = ph;
      *(u16x8*)&Bs[1][bkg][bn][0] = pl;
      *(u16x8*)&Bs[2][bkg][bn][0] = pq;
    }
    __syncthreads();
    if (s + 1 < nsteps) { // prefetch next step
      int kk = (s + 1) * 32;
      const float* ap = xrow + (size_t)am * DD + kk + akg * 8;
      aR0 = *(const float4*)ap;       aR1 = *(const float4*)(ap + 4);
      const float* ap2 = ap + (size_t)64 * DD;
      aR2 = *(const float4*)ap2;      aR3 = *(const float4*)(ap2 + 4);
      const float* wp = wrow + (size_t)bn * DD + kk + bkg * 8;
      bR0 = *(const float4*)wp;       bR1 = *(const float4*)(wp + 4);
    }
    bf16x8 af[2][2];
    #pragma unroll
    for (int mf = 0; mf < 2; mf++)
      #pragma unroll
      for (int h = 0; h < 2; h++)
        af[mf][h] = *(const bf16x8*)&As[2 * h + lh][wr + mf * 32 + lm][0];
    #pragma unroll
    for (int p = 0; p < 3; p++) {
      bf16x8 b0 = *(const bf16x8*)&Bs[p][lh][wc + lm][0];
      bf16x8 b1 = *(const bf16x8*)&Bs[p][2 + lh][wc + lm][0];
      #pragma unroll
      for (int mf = 0; mf < 2; mf++) {
        acc[mf] = __builtin_amdgcn_mfma_f32_32x32x16_bf16(af[mf][0], b0, acc[mf], 0, 0, 0);
        acc[mf] = __builtin_amdgcn_mfma_f32_32x32x16_bf16(af[mf][1], b1, acc[mf], 0, 0, 0);
      }
    }
  }

  float* Cp = Cpart + (size_t)kc * ((size_t)BB * DD);
  #pragma unroll
  for (int mf = 0; mf < 2; mf++) {
    int col   = nt * 64 + wc + lm;
    int rbase = mt * 128 + wr + mf * 32 + 4 * lh;
    #pragma unroll
    for (int r = 0; r < 16; r++) {
      int row = rbase + (r & 3) + 8 * (r >> 2);
      Cp[(size_t)row * DD + col] = acc[mf][r];
    }
  }
}

// ---------------- K_FILTER: threefry u-filter, forced 4-way ILP hash chains ----------------
__global__ __launch_bounds__(256) void k_filter(
    u16* __restrict__ flt_list, int* __restrict__ flt_cnt) {
  int t = threadIdx.x;
  int fb = blockIdx.x;
  int b = fb / MAXR, j = fb % MAXR;
  unsigned kk0, kk1;
  keys_of(j, kk0, kk1);                 // block-uniform -> SALU
  unsigned base_c = (unsigned)(b * DD);
  // integer threshold: pass <=> bits_to_unit(bits) >= U_THRESH  <=>  (bits>>9) >= KMIN
  const unsigned KMIN = (unsigned)ceil((double)U_THRESH * 8388608.0);

  __shared__ int fcnt;
  __shared__ u16 fl[CAPG];
  if (t == 0) fcnt = 0;
  __syncthreads();

  #pragma unroll
  for (int p = 0; p < 4; p++) {
    unsigned c1[4], bits[4];
    #pragma unroll
    for (int q = 0; q < 4; q++) c1[q] = base_c + (unsigned)(t + 256 * (4 * p + q));
    tf_xor_x4(kk0, kk1, c1, bits);      // 4 forced-live chains in flight
    #pragma unroll
    for (int q = 0; q < 4; q++) {
      if ((bits[q] >> 9) >= KMIN) {
        int pos = atomicAdd(&fcnt, 1);
        if (pos < CAPG) fl[pos] = (u16)(t + 256 * (4 * p + q));
      }
    }
  }
  __syncthreads();
  int n = fcnt;
  if (t == 0) flt_cnt[fb] = n;
  int nstore = n < CAPG ? n : CAPG;
  if (t < nstore) flt_list[(size_t)fb * CAPG + t] = fl[t];
}

// ---------------- K_TAIL: everything after the GEMM, one block per batch row ----------
// phases: A reduce+score  B top4 (one j per wave, butterfly)  (B') exact fallback
//         C chain-select  D y/grad_y/score_y                  E accept+output
__global__ __launch_bounds__(1024) void k_tail(
    const float* __restrict__ Cpart, const float* __restrict__ bias,
    const float* __restrict__ x, const float* __restrict__ W,
    const u16* __restrict__ flt_list, const int* __restrict__ flt_cnt,
    float* __restrict__ out, int KS) {
  int b = blockIdx.x, t = threadIdx.x;

  __shared__ float sc_lds[DD];        // 16 KB: sc_x
  __shared__ float gr_lds[DD];        // 16 KB: grad_x, then sc_y
  __shared__ double redbuf[16];
  __shared__ float lmx[16];
  __shared__ float ls_v[16];
  __shared__ int   ls_i[16];
  __shared__ int   win_i[4];
  __shared__ int   cand_lds[MAXR][NCAND];
  __shared__ int   fb_list[MAXR];
  __shared__ int   nfb_s;
  __shared__ int   fidx[MAXR];
  __shared__ float fsgn[MAXR];
  __shared__ unsigned mask[DD / 32];
  __shared__ int   pick_s;
  __shared__ int   nf_s;
  __shared__ float scmax_s;
  __shared__ double score_x_s, score_y_s, Ssum_s, Tsum_s;
  __shared__ float scx_s[MAXR], scy_s[MAXR];
  __shared__ float accf;

  // ================= phase A: split-K reduce, sc_x, score_x, scmax, S =================
  int d0 = t * 4;
  size_t o = (size_t)b * DD + d0;
  float a0 = 0.f, a1 = 0.f, a2 = 0.f, a3 = 0.f;
  for (int kc = 0; kc < KS; kc++) {
    float4 c = *(const float4*)&Cpart[(size_t)kc * BB * DD + o];
    a0 += c.x; a1 += c.y; a2 += c.z; a3 += c.w;
  }
  float4 bv4 = *(const float4*)&bias[d0];
  float4 xv4 = *(const float4*)&x[o];
  float gg[4] = { a0 + bv4.x, a1 + bv4.y, a2 + bv4.z, a3 + bv4.w };
  float xx[4] = { xv4.x, xv4.y, xv4.z, xv4.w };
  float bb[4] = { bv4.x, bv4.y, bv4.z, bv4.w };
  float scv[4];
  double s1 = 0.0, s2 = 0.0;
  float mx = -INFINITY;
  #pragma unroll
  for (int k = 0; k < 4; k++) {
    scv[k] = (1.0f - 2.0f * xx[k]) * gg[k] * 0.5f;
    mx = fmaxf(mx, scv[k]);
    s1 += (double)xx[k] * (double)gg[k];
    s2 += (double)xx[k] * (double)bb[k];
  }
  *(float4*)&sc_lds[d0] = *(float4*)&scv[0];
  *(float4*)&gr_lds[d0] = *(float4*)&gg[0];
  if (t < 128) mask[t] = 0u;
  if (t == 0) { nf_s = radius_of(b); nfb_s = 0; }
  double sx = exp((double)scv[0]) + exp((double)scv[1]) + exp((double)scv[2]) + exp((double)scv[3]);
  double S1 = blockReduce1024(s1, redbuf);
  double S2 = blockReduce1024(s2, redbuf);
  double Sv = blockReduce1024(sx, redbuf);
  #pragma unroll
  for (int off = 32; off > 0; off >>= 1) mx = fmaxf(mx, __shfl_down(mx, off));
  __syncthreads();
  if ((t & 63) == 0) lmx[t >> 6] = mx;
  __syncthreads();
  if (t == 0) {
    float m = lmx[0];
    #pragma unroll
    for (int i = 1; i < 16; i++) m = fmaxf(m, lmx[i]);
    score_x_s = 0.5 * (S1 + S2);
    scmax_s = m;
    Ssum_s = Sv;
  }
  __syncthreads();

  // ======== phase B: top-4, one j per wave, butterfly reduce (no barriers) ========
  {
    int wv = t >> 6, ln = t & 63;
    float scmax_l = scmax_s;
    for (int pass = 0; pass < 2; pass++) {
      int j = pass * 16 + wv;
      if (j < MAXR) {
        unsigned kk0, kk1;
        keys_of(j, kk0, kk1);
        int n = flt_cnt[b * MAXR + j];
        bool fastok = !(n > CAPG || n < NCAND);
        float v4 = -INFINITY;
        if (fastok) {
          const u16* fl = &flt_list[(size_t)(b * MAXR + j) * CAPG];
          float vv[3]; int dd[3]; unsigned alive = 0u;
          #pragma unroll
          for (int q = 0; q < 3; q++) {
            int idx = ln + 64 * q;
            if (idx < n) {
              int d = (int)fl[idx];
              float f = bits_to_unit(tf_xor(kk0, kk1, 0u, (unsigned)(b * DD) + (unsigned)d));
              vv[q] = sc_lds[d] + gumbel_from_u(f);
              dd[q] = d;
              alive |= 1u << q;
            } else { vv[q] = -INFINITY; dd[q] = 0x7FFFFFFF; }
          }
          for (int r = 0; r < NCAND; r++) {
            float bv = -INFINITY; int bi = 0x7FFFFFFF;
            #pragma unroll
            for (int q = 0; q < 3; q++)
              if (((alive >> q) & 1u) && (vv[q] > bv || (vv[q] == bv && dd[q] < bi))) { bv = vv[q]; bi = dd[q]; }
            #pragma unroll
            for (int off = 1; off < 64; off <<= 1) {
              float ov = __shfl_xor(bv, off);
              int   oi = __shfl_xor(bi, off);
              if (ov > bv || (ov == bv && oi < bi)) { bv = ov; bi = oi; }
            }
            // all 64 lanes agree on (bv, bi)
            if (ln == 0) cand_lds[j][r] = bi;
            v4 = bv;
            #pragma unroll
            for (int q = 0; q < 3; q++) if (dd[q] == bi) alive &= ~(1u << q);
          }
        }
        if (ln == 0) {
          bool needfb = !fastok || (v4 < scmax_l + GUARD);
          if (needfb) fb_list[atomicAdd(&nfb_s, 1)] = j;
        }
      }
    }
  }
  __syncthreads();

  // ================= phase B': exact fallback (statistically ~never) =================
  int nfb = nfb_s;
  for (int fi = 0; fi < nfb; fi++) {
    int j = fb_list[fi];
    unsigned kk0, kk1;
    keys_of(j, kk0, kk1);
    float vq[4]; int dq[4];
    unsigned alive = 0xFu;
    #pragma unroll
    for (int q = 0; q < 4; q++) {
      int d = t * 4 + q;
      vq[q] = sc_lds[d] + gumbel_of(kk0, kk1, (unsigned)(b * DD + d));
      dq[q] = d;
    }
    for (int r = 0; r < NCAND; r++) {
      float lv = -INFINITY; int li = 0x7FFFFFFF;
      #pragma unroll
      for (int q = 0; q < 4; q++)
        if (((alive >> q) & 1u) && (vq[q] > lv || (vq[q] == lv && dq[q] < li))) { lv = vq[q]; li = dq[q]; }
      #pragma unroll
      for (int off = 32; off > 0; off >>= 1) {
        float ov = __shfl_down(lv, off);
        int   oi = __shfl_down(li, off);
        if (ov > lv || (ov == lv && oi < li)) { lv = ov; li = oi; }
      }
      if ((t & 63) == 0) { ls_v[t >> 6] = lv; ls_i[t >> 6] = li; }
      __syncthreads();
      if (t == 0) {
        float fv = ls_v[0]; int fi2 = ls_i[0];
        #pragma unroll
        for (int w = 1; w < 16; w++)
          if (ls_v[w] > fv || (ls_v[w] == fv && ls_i[w] < fi2)) { fv = ls_v[w]; fi2 = ls_i[w]; }
        cand_lds[j][r] = fi2;
        win_i[0] = fi2;
      }
      __syncthreads();
      int wi = win_i[0];
      #pragma unroll
      for (int q = 0; q < 4; q++) if (dq[q] == wi) alive &= ~(1u << q);
    }
    __syncthreads();
  }

  // ================= phase C: blocked-chain resolution =================
  int jdone = 0;
  while (true) {
    if (t == 0) {
      int j = jdone;
      while (j < MAXR) {
        int pick = -1;
        #pragma unroll
        for (int r = 0; r < NCAND; r++) {
          int idx = cand_lds[j][r];
          if (pick < 0 && !((mask[idx >> 5] >> (idx & 31)) & 1u)) pick = idx;
        }
        if (pick < 0) break;
        fidx[j] = pick;
        mask[pick >> 5] |= (1u << (pick & 31));
        j++;
      }
      pick_s = j;
    }
    __syncthreads();
    int jf = pick_s;
    if (jf >= MAXR) break;
    { // cooperative exact fallback for step jf
      unsigned kk0, kk1;
      keys_of(jf, kk0, kk1);
      float lv = -INFINITY; int li = 0x7FFFFFFF;
      #pragma unroll
      for (int q = 0; q < 4; q++) {
        int d = t * 4 + q;
        if ((mask[d >> 5] >> (d & 31)) & 1u) continue;
        float vv = sc_lds[d] + gumbel_of(kk0, kk1, (unsigned)(b * DD + d));
        if (vv > lv || (vv == lv && d < li)) { lv = vv; li = d; }
      }
      #pragma unroll
      for (int off = 32; off > 0; off >>= 1) {
        float ov = __shfl_down(lv, off);
        int   oi = __shfl_down(li, off);
        if (ov > lv || (ov == lv && oi < li)) { lv = ov; li = oi; }
      }
      if ((t & 63) == 0) { ls_v[t >> 6] = lv; ls_i[t >> 6] = li; }
      __syncthreads();
      if (t == 0) {
        float fv = ls_v[0]; int fi2 = ls_i[0];
        #pragma unroll
        for (int w = 1; w < 16; w++)
          if (ls_v[w] > fv || (ls_v[w] == fv && ls_i[w] < fi2)) { fv = ls_v[w]; fi2 = ls_i[w]; }
        fidx[jf] = fi2;
        mask[fi2 >> 5] |= (1u << (fi2 & 31));
      }
      __syncthreads();
    }
    jdone = jf + 1;
  }

  int nf = nf_s;
  if (t < nf) fsgn[t] = 1.0f - 2.0f * x[(size_t)b * DD + fidx[t]];
  __syncthreads();

  // ================= phase D: y, grad_y, sc_y, score_y, T =================
  float gd[4] = { gr_lds[d0], gr_lds[d0 + 1], gr_lds[d0 + 2], gr_lds[d0 + 3] };
  float yy[4] = { xx[0], xx[1], xx[2], xx[3] };
  for (int jj = 0; jj < nf; jj++) {
    int fd = fidx[jj];
    float s = fsgn[jj];
    float4 wv = *(const float4*)&W[(size_t)fd * DD + d0];
    gd[0] = fmaf(s, wv.x, gd[0]);
    gd[1] = fmaf(s, wv.y, gd[1]);
    gd[2] = fmaf(s, wv.z, gd[2]);
    gd[3] = fmaf(s, wv.w, gd[3]);
    int r = fd - d0;
    if (r >= 0 && r < 4) yy[r] = 1.0f - xx[r];
  }
  float scy[4];
  double t1 = 0.0, t2 = 0.0;
  #pragma unroll
  for (int k = 0; k < 4; k++) {
    scy[k] = (1.0f - 2.0f * yy[k]) * gd[k] * 0.5f;
    t1 += (double)yy[k] * (double)gd[k];
    t2 += (double)yy[k] * (double)bb[k];
  }
  double sy = exp((double)scy[0]) + exp((double)scy[1]) + exp((double)scy[2]) + exp((double)scy[3]);
  __syncthreads();               // all reads of gr_lds (phase D gd init) complete
  *(float4*)&gr_lds[d0] = *(float4*)&scy[0];   // gr_lds now holds sc_y
  double T1 = blockReduce1024(t1, redbuf);
  double T2 = blockReduce1024(t2, redbuf);
  double Tv = blockReduce1024(sy, redbuf);
  if (t == 0) { score_y_s = 0.5 * (T1 + T2); Tsum_s = Tv; }
  __syncthreads();

  // ================= phase E: accept + output =================
  if (t < MAXR) {
    int id = fidx[t];
    scx_s[t] = sc_lds[id];
    scy_s[t] = gr_lds[id];
  }
  __syncthreads();
  if (t < 32) {
    int lane = t;
    double S = Ssum_s, T = Tsum_s;
    double ex = (t < MAXR) ? exp((double)scx_s[t]) : 0.0;
    double scn = ex;
    #pragma unroll
    for (int off = 1; off < 32; off <<= 1) {
      double ov = __shfl_up(scn, off);
      if (lane >= off) scn += ov;
    }
    double pre = scn - ex;
    double gf = (t < nf) ? ((double)scx_s[t] - dlog(S - pre)) : 0.0;
    double ey = (t < MAXR) ? exp((double)scy_s[t]) : 0.0;
    double scn2 = ey;
    #pragma unroll
    for (int off = 1; off < 32; off <<= 1) {
      double ov = __shfl_down(scn2, off);
      if (lane + off < 32) scn2 += ov;
    }
    double suf = scn2 - ey;
    double gb = (t < nf) ? ((double)scy_s[t] - dlog(T - suf)) : 0.0;
    #pragma unroll
    for (int off = 16; off > 0; off >>= 1) {
      gf += __shfl_down(gf, off);
      gb += __shfl_down(gb, off);
    }
    if (t == 0) {
      double log_acc = (gb + score_y_s) - (gf + score_x_s);
      accf = (exp(log_acc) >= (double)uacc_of(b)) ? 1.0f : 0.0f;
    }
  }
  __syncthreads();
  float a = accf;
  float4 ov4;
  ov4.x = a * yy[0] + (1.0f - a) * xx[0];
  ov4.y = a * yy[1] + (1.0f - a) * xx[1];
  ov4.z = a * yy[2] + (1.0f - a) * xx[2];
  ov4.w = a * yy[3] + (1.0f - a) * xx[3];
  *(float4*)&out[o] = ov4;
}

extern "C" void kernel_launch(void* const* d_in, const int* in_sizes, int n_in,
                              void* d_out, int out_size, void* d_ws, size_t ws_size,
                              hipStream_t stream) {
  const float* x    = (const float*)d_in[0];
  const float* W    = (const float*)d_in[1];
  const float* bias = (const float*)d_in[2];
  float* out = (float*)d_out;
  char* ws = (char*)d_ws;
  const size_t MB = 1ull << 20;

  u16*    flt_list = (u16*)(ws + 0*MB);             // 7936*192*2 = 2.91 MB
  int*    flt_cnt  = (int*)(ws + 3*MB);             // 32 KB
  float*  Cpart    = (float*)(ws + 4*MB);           // KS * 4 MB

  size_t base = 4*MB;
  int KS = 1;
  if      (ws_size >= base + 16*MB) KS = 4;
  else if (ws_size >= base +  8*MB) KS = 2;

  int NG = 64 * 2 * KS;   // N-tiles x M-tiles x split-K

  k_filter<<<BB*MAXR, 256, 0, stream>>>(flt_list, flt_cnt);
  k_gemm  <<<NG, 256, 0, stream>>>(x, W, Cpart, DD/KS);
  k_tail  <<<BB, 1024, 0, stream>>>(Cpart, bias, x, W, flt_list, flt_cnt, out, KS);
}